// Round 1
// baseline (2276.137 us; speedup 1.0000x reference)
//
#include <hip/hip_runtime.h>
#include <hip/hip_bf16.h>

#define BK 16
#define LDT 68  // padded LDS tile row stride (floats), keeps float4 alignment

__device__ __forceinline__ float sigmoidf_(float x) { return 1.0f / (1.0f + __expf(-x)); }
__device__ __forceinline__ float siluf_(float x) { return x * sigmoidf_(x); }
__device__ __forceinline__ float softplusf_(float x) {
    return fmaxf(x, 0.0f) + log1pf(__expf(-fabsf(x)));
}

// ---------------------------------------------------------------------------
// K1: fused input projections.
//   dec[b,l,c] = decoder_feat[b,c,l]  (K-major for the GEMM -> coalesced)
//   dec_x   = dec @ dec_w[:, :512] + dec_b[:512]
//   dec_g   = dec @ dec_w[:, 512:] + dec_b[512:]
//   enc_p   = enc @ enc_w + enc_b
//   combined = dec_x * sigmoid(enc_p) + enc_p
// M=8192, N=512, K=256
// ---------------------------------------------------------------------------
__global__ __launch_bounds__(256) void k_fuse_in(
    const float* __restrict__ dec, const float* __restrict__ enc,
    const float* __restrict__ dec_w, const float* __restrict__ dec_b,
    const float* __restrict__ enc_w, const float* __restrict__ enc_b,
    float* __restrict__ combined, float* __restrict__ dec_gate)
{
    __shared__ float Ad[BK * LDT], Ae[BK * LDT];
    __shared__ float Bx[BK * LDT], Bg[BK * LDT], Be[BK * LDT];
    const int tid = threadIdx.x;
    const int n0 = blockIdx.x * 64;
    const int m0 = blockIdx.y * 64;
    const int bidx = m0 >> 12;
    const int l0 = m0 & 4095;
    const int tx = tid & 15, ty = tid >> 4;
    float ax[4][4] = {}, ag[4][4] = {}, ae_[4][4] = {};
    const int kl = tid >> 4;        // 0..15
    const int mq = (tid & 15) * 4;  // A column (m) quad
    const size_t CL = 256 * 4096;

    for (int k0 = 0; k0 < 256; k0 += BK) {
        float4 vad = *(const float4*)&dec[(size_t)bidx * CL + (size_t)(k0 + kl) * 4096 + l0 + mq];
        float4 vae = *(const float4*)&enc[(size_t)bidx * CL + (size_t)(k0 + kl) * 4096 + l0 + mq];
        float4 vbx = *(const float4*)&dec_w[(size_t)(k0 + kl) * 1024 + n0 + mq];
        float4 vbg = *(const float4*)&dec_w[(size_t)(k0 + kl) * 1024 + 512 + n0 + mq];
        float4 vbe = *(const float4*)&enc_w[(size_t)(k0 + kl) * 512 + n0 + mq];
        *(float4*)&Ad[kl * LDT + mq] = vad;
        *(float4*)&Ae[kl * LDT + mq] = vae;
        *(float4*)&Bx[kl * LDT + mq] = vbx;
        *(float4*)&Bg[kl * LDT + mq] = vbg;
        *(float4*)&Be[kl * LDT + mq] = vbe;
        __syncthreads();
#pragma unroll
        for (int kk = 0; kk < BK; ++kk) {
            float4 a1 = *(const float4*)&Ad[kk * LDT + ty * 4];
            float4 a2 = *(const float4*)&Ae[kk * LDT + ty * 4];
            float4 b1 = *(const float4*)&Bx[kk * LDT + tx * 4];
            float4 b2 = *(const float4*)&Bg[kk * LDT + tx * 4];
            float4 b3 = *(const float4*)&Be[kk * LDT + tx * 4];
            float av1[4] = {a1.x, a1.y, a1.z, a1.w};
            float av2[4] = {a2.x, a2.y, a2.z, a2.w};
            float bx_[4] = {b1.x, b1.y, b1.z, b1.w};
            float bg_[4] = {b2.x, b2.y, b2.z, b2.w};
            float be2[4] = {b3.x, b3.y, b3.z, b3.w};
#pragma unroll
            for (int i = 0; i < 4; ++i)
#pragma unroll
                for (int j = 0; j < 4; ++j) {
                    ax[i][j] = fmaf(av1[i], bx_[j], ax[i][j]);
                    ag[i][j] = fmaf(av1[i], bg_[j], ag[i][j]);
                    ae_[i][j] = fmaf(av2[i], be2[j], ae_[i][j]);
                }
        }
        __syncthreads();
    }
#pragma unroll
    for (int i = 0; i < 4; ++i) {
        int m = m0 + ty * 4 + i;
#pragma unroll
        for (int j = 0; j < 4; ++j) {
            int n = n0 + tx * 4 + j;
            float dx = ax[i][j] + dec_b[n];
            float dg = ag[i][j] + dec_b[512 + n];
            float ep = ae_[i][j] + enc_b[n];
            combined[(size_t)m * 512 + n] = dx * sigmoidf_(ep) + ep;
            dec_gate[(size_t)m * 512 + n] = dg;
        }
    }
}

// ---------------------------------------------------------------------------
// Generic row-major SGEMM with compile-time epilogue.
// EPI 0: xz split     -> n<512: out0[m,n]=v ; n>=512: out1[m,n-512]=silu(v)
// EPI 1: mamba out    -> out0[m,n] = v * sigmoid(extra[m,n])   (extra=dec_gate)
// EPI 2: out proj     -> out0[m,n] = v + decoder_feat[b,n,l]   (extra=decoder)
// ---------------------------------------------------------------------------
template <int EPI>
__global__ __launch_bounds__(256) void sgemm_k(
    const float* __restrict__ A, const float* __restrict__ Bw,
    const float* __restrict__ bias, float* __restrict__ out0,
    float* __restrict__ out1, const float* __restrict__ extra,
    int M, int N, int K)
{
    __shared__ float As[BK * LDT];
    __shared__ float Bs[BK * LDT];
    const int tid = threadIdx.x;
    const int n0 = blockIdx.x * 64;
    const int m0 = blockIdx.y * 64;
    const int tx = tid & 15, ty = tid >> 4;
    float acc[4][4] = {};
    const int am = tid >> 2;         // 0..63 (m row)
    const int ak = (tid & 3) * 4;    // k quad
    const int bk = tid >> 4;         // 0..15 (k row)
    const int bn = (tid & 15) * 4;   // n quad

    for (int k0 = 0; k0 < K; k0 += BK) {
        float4 va = *(const float4*)&A[(size_t)(m0 + am) * K + k0 + ak];
        float4 vb = *(const float4*)&Bw[(size_t)(k0 + bk) * N + n0 + bn];
        As[(ak + 0) * LDT + am] = va.x;
        As[(ak + 1) * LDT + am] = va.y;
        As[(ak + 2) * LDT + am] = va.z;
        As[(ak + 3) * LDT + am] = va.w;
        *(float4*)&Bs[bk * LDT + bn] = vb;
        __syncthreads();
#pragma unroll
        for (int kk = 0; kk < BK; ++kk) {
            float4 a = *(const float4*)&As[kk * LDT + ty * 4];
            float4 b = *(const float4*)&Bs[kk * LDT + tx * 4];
            float av[4] = {a.x, a.y, a.z, a.w};
            float bv[4] = {b.x, b.y, b.z, b.w};
#pragma unroll
            for (int i = 0; i < 4; ++i)
#pragma unroll
                for (int j = 0; j < 4; ++j)
                    acc[i][j] = fmaf(av[i], bv[j], acc[i][j]);
        }
        __syncthreads();
    }
#pragma unroll
    for (int i = 0; i < 4; ++i) {
        int m = m0 + ty * 4 + i;
#pragma unroll
        for (int j = 0; j < 4; ++j) {
            int n = n0 + tx * 4 + j;
            float v = acc[i][j] + bias[n];
            if (EPI == 0) {
                if (n < 512) out0[(size_t)m * 512 + n] = v;
                else         out1[(size_t)m * 512 + (n - 512)] = siluf_(v);
            } else if (EPI == 1) {
                float g = extra[(size_t)m * 512 + n];
                out0[(size_t)m * 512 + n] = v * sigmoidf_(g);
            } else {
                int b = m >> 12, l = m & 4095;
                float dv = extra[(size_t)b * (256 * 4096) + (size_t)n * 4096 + l];
                out0[(size_t)m * 256 + n] = v + dv;
            }
        }
    }
}

// ---------------------------------------------------------------------------
// K3+K4: depthwise causal conv (K=4) + silu -> u ; x_dbl = u @ x_proj_w ;
//        dt = softplus(x_dbl[:, :32] @ dt_w + dt_b) ; store Bm, Cm.
// One block per row bl.
// ---------------------------------------------------------------------------
__global__ __launch_bounds__(256) void k_conv_proj(
    const float* __restrict__ xm, const float* __restrict__ conv_w,
    const float* __restrict__ conv_b, const float* __restrict__ x_proj_w,
    const float* __restrict__ dt_w, const float* __restrict__ dt_b,
    float* __restrict__ u_out, float* __restrict__ Bm, float* __restrict__ Cm,
    float* __restrict__ dt_out)
{
    __shared__ float us[512];
    __shared__ float part[4][64];
    __shared__ float xd[64];
    const int tid = threadIdx.x;
    const int bl = blockIdx.x;
    const int l = bl & 4095;

#pragma unroll
    for (int dd = 0; dd < 2; ++dd) {
        int d = tid + dd * 256;
        float acc = conv_b[d];
#pragma unroll
        for (int k = 0; k < 4; ++k) {
            int ll = l - 3 + k;
            if (ll >= 0) acc = fmaf(conv_w[d * 4 + k], xm[(size_t)(bl - 3 + k) * 512 + d], acc);
        }
        float uv = siluf_(acc);
        us[d] = uv;
        u_out[(size_t)bl * 512 + d] = uv;
    }
    __syncthreads();

    {   // x_dbl: 64 outputs, 4 k-slices of 128 each
        int j = tid & 63;
        int s = tid >> 6;
        float p = 0.f;
        for (int k = s * 128; k < s * 128 + 128; ++k)
            p = fmaf(us[k], x_proj_w[(size_t)k * 64 + j], p);
        part[s][j] = p;
    }
    __syncthreads();
    if (tid < 64) {
        float v = part[0][tid] + part[1][tid] + part[2][tid] + part[3][tid];
        xd[tid] = v;
        if (tid >= 32 && tid < 48)      Bm[(size_t)bl * 16 + (tid - 32)] = v;
        else if (tid >= 48)             Cm[(size_t)bl * 16 + (tid - 48)] = v;
    }
    __syncthreads();

#pragma unroll
    for (int dd = 0; dd < 2; ++dd) {
        int d = tid + dd * 256;
        float a = dt_b[d];
#pragma unroll
        for (int r = 0; r < 32; ++r)
            a = fmaf(xd[r], dt_w[(size_t)r * 512 + d], a);
        dt_out[(size_t)bl * 512 + d] = softplusf_(a);
    }
}

// ---------------------------------------------------------------------------
// K5: selective scan. One lane per (b,d,n); 16-lane reduce for y;
//     fused y = (y + u*D) * silu(z).
// ---------------------------------------------------------------------------
__global__ __launch_bounds__(256) void k_scan(
    const float* __restrict__ dt, const float* __restrict__ u,
    const float* __restrict__ Bmp, const float* __restrict__ Cmp,
    const float* __restrict__ A_log, const float* __restrict__ Dp,
    const float* __restrict__ zs, float* __restrict__ yout)
{
    const int gid = blockIdx.x * 256 + threadIdx.x;
    const int b = gid >> 13;
    const int rem = gid & 8191;
    const int d = rem >> 4;
    const int n = rem & 15;
    const float Av = -__expf(A_log[d * 16 + n]);
    const float Dv = Dp[d];
    const size_t rb = (size_t)b * 4096;
    const float* dtp = dt + rb * 512 + d;
    const float* up = u + rb * 512 + d;
    const float* Bp = Bmp + rb * 16 + n;
    const float* Cp = Cmp + rb * 16 + n;
    const float* zp = zs + rb * 512 + d;
    float* yp = yout + rb * 512 + d;

    float h = 0.f;
    float dtv = dtp[0], uv = up[0], Bv = Bp[0], Cv = Cp[0];
    for (int l = 0; l < 4096; ++l) {
        float dtn = 0.f, un = 0.f, Bn = 0.f, Cn = 0.f;
        if (l + 1 < 4096) {
            size_t o5 = (size_t)(l + 1) * 512;
            size_t o1 = (size_t)(l + 1) * 16;
            dtn = dtp[o5]; un = up[o5]; Bn = Bp[o1]; Cn = Cp[o1];
        }
        float dA = __expf(dtv * Av);
        h = fmaf(h, dA, dtv * uv * Bv);
        float y = h * Cv;
        y += __shfl_xor(y, 1);
        y += __shfl_xor(y, 2);
        y += __shfl_xor(y, 4);
        y += __shfl_xor(y, 8);
        if (n == 0) {
            yp[(size_t)l * 512] = (y + uv * Dv) * zp[(size_t)l * 512];
        }
        dtv = dtn; uv = un; Bv = Bn; Cv = Cn;
    }
}

// ---------------------------------------------------------------------------
// K7b: LayerNorm over C=256 + transpose write to (B,C,H,W).
// One block per (b, 64-row l chunk).
// ---------------------------------------------------------------------------
__global__ __launch_bounds__(256) void k_ln_t(
    const float* __restrict__ res, const float* __restrict__ ln_g,
    const float* __restrict__ ln_b, float* __restrict__ outp)
{
    __shared__ float r[64 * 257];
    __shared__ float red[64][8];
    __shared__ float mu_s[64], sc_s[64];
    const int tid = threadIdx.x;
    const int b = blockIdx.x >> 6;
    const int l0 = (blockIdx.x & 63) * 64;
    const size_t base = ((size_t)b * 4096 + l0) * 256;

    for (int e = tid; e < 64 * 256; e += 256) {
        int i = e >> 8;
        int c = e & 255;
        r[i * 257 + c] = res[base + (size_t)i * 256 + c];
    }
    __syncthreads();
    {
        int i = tid >> 2, s = tid & 3;
        float ps = 0.f, pq = 0.f;
        for (int c = s * 64; c < s * 64 + 64; ++c) {
            float v = r[i * 257 + c];
            ps += v;
            pq = fmaf(v, v, pq);
        }
        red[i][s] = ps;
        red[i][4 + s] = pq;
    }
    __syncthreads();
    if (tid < 64) {
        float ps = red[tid][0] + red[tid][1] + red[tid][2] + red[tid][3];
        float pq = red[tid][4] + red[tid][5] + red[tid][6] + red[tid][7];
        float mu = ps * (1.0f / 256.0f);
        float var = pq * (1.0f / 256.0f) - mu * mu;
        mu_s[tid] = mu;
        sc_s[tid] = rsqrtf(var + 1e-5f);
    }
    __syncthreads();
    const int il = tid & 63;
    const int cg = tid >> 6;
    const float mu = mu_s[il], sc = sc_s[il];
    for (int c = cg; c < 256; c += 4) {
        float v = (r[il * 257 + c] - mu) * sc * ln_g[c] + ln_b[c];
        outp[(size_t)b * (256 * 4096) + (size_t)c * 4096 + l0 + il] = v;
    }
}

// ---------------------------------------------------------------------------
extern "C" void kernel_launch(void* const* d_in, const int* in_sizes, int n_in,
                              void* d_out, int out_size, void* d_ws, size_t ws_size,
                              hipStream_t stream)
{
    const float* decoder_feat = (const float*)d_in[0];
    const float* encoder_feat = (const float*)d_in[1];
    const float* dec_w = (const float*)d_in[2];
    const float* dec_b = (const float*)d_in[3];
    const float* enc_w = (const float*)d_in[4];
    const float* enc_b = (const float*)d_in[5];
    const float* out_w = (const float*)d_in[6];
    const float* out_b = (const float*)d_in[7];
    const float* ln_g = (const float*)d_in[8];
    const float* ln_bb = (const float*)d_in[9];
    const float* in_w = (const float*)d_in[10];
    const float* in_b = (const float*)d_in[11];
    const float* conv_w = (const float*)d_in[12];
    const float* conv_b = (const float*)d_in[13];
    const float* x_proj_w = (const float*)d_in[14];
    const float* dt_w = (const float*)d_in[15];
    const float* dt_b = (const float*)d_in[16];
    const float* A_log = (const float*)d_in[17];
    const float* D_param = (const float*)d_in[18];
    const float* m_out_w = (const float*)d_in[19];
    const float* m_out_b = (const float*)d_in[20];

    float* outp = (float*)d_out;
    float* ws = (float*)d_ws;
    const size_t S = 8192ull * 512;  // 4M floats per slot
    float* combined = ws;            // slot0: combined, later y_final
    float* dec_gate = ws + S;        // slot1
    float* xm       = ws + 2 * S;    // slot2: xm, later gated
    float* z_silu   = ws + 3 * S;    // slot3
    float* u_buf    = ws + 4 * S;    // slot4
    float* dt_buf   = ws + 5 * S;    // slot5: dt, later res (2M floats)
    float* Bm       = ws + 6 * S;          // 131072 floats
    float* Cm       = ws + 6 * S + 131072; // 131072 floats

    // 1) input projections + cross gate
    k_fuse_in<<<dim3(8, 128), 256, 0, stream>>>(
        decoder_feat, encoder_feat, dec_w, dec_b, enc_w, enc_b, combined, dec_gate);
    // 2) xz = combined @ in_w -> xm, silu(z)
    sgemm_k<0><<<dim3(16, 128), 256, 0, stream>>>(
        combined, in_w, in_b, xm, z_silu, nullptr, 8192, 1024, 512);
    // 3) conv + silu -> u ; x_dbl ; dt ; Bm ; Cm
    k_conv_proj<<<8192, 256, 0, stream>>>(
        xm, conv_w, conv_b, x_proj_w, dt_w, dt_b, u_buf, Bm, Cm, dt_buf);
    // 4) selective scan -> y_final (into slot0)
    k_scan<<<64, 256, 0, stream>>>(
        dt_buf, u_buf, Bm, Cm, A_log, D_param, z_silu, combined);
    // 5) gated = (y @ m_out_w + b) * sigmoid(dec_gate)  (into slot2)
    sgemm_k<1><<<dim3(8, 128), 256, 0, stream>>>(
        combined, m_out_w, m_out_b, xm, nullptr, dec_gate, 8192, 512, 512);
    // 6) res = gated @ out_w + out_b + dec  (into slot5)
    sgemm_k<2><<<dim3(4, 128), 256, 0, stream>>>(
        xm, out_w, out_b, dt_buf, nullptr, decoder_feat, 8192, 256, 512);
    // 7) LayerNorm + transpose to (B,C,H,W)
    k_ln_t<<<128, 256, 0, stream>>>(dt_buf, ln_g, ln_bb, outp);
}

// Round 2
// 610.787 us; speedup vs baseline: 3.7266x; 3.7266x over previous
//
#include <hip/hip_runtime.h>
#include <hip/hip_bf16.h>

#define BK 16
#define LDT 68  // padded LDS tile row stride (floats), keeps float4 alignment

__device__ __forceinline__ float sigmoidf_(float x) { return 1.0f / (1.0f + __expf(-x)); }
__device__ __forceinline__ float siluf_(float x) { return x * sigmoidf_(x); }
__device__ __forceinline__ float softplusf_(float x) {
    return fmaxf(x, 0.0f) + log1pf(__expf(-fabsf(x)));
}

// ---------------------------------------------------------------------------
// K1: fused input projections.
//   dec[b,l,c] = decoder_feat[b,c,l]  (K-major for the GEMM -> coalesced)
//   combined = dec_x * sigmoid(enc_p) + enc_p ; dec_gate stored raw.
// M=8192, N=512, K=256
// ---------------------------------------------------------------------------
__global__ __launch_bounds__(256) void k_fuse_in(
    const float* __restrict__ dec, const float* __restrict__ enc,
    const float* __restrict__ dec_w, const float* __restrict__ dec_b,
    const float* __restrict__ enc_w, const float* __restrict__ enc_b,
    float* __restrict__ combined, float* __restrict__ dec_gate)
{
    __shared__ float Ad[BK * LDT], Ae[BK * LDT];
    __shared__ float Bx[BK * LDT], Bg[BK * LDT], Be[BK * LDT];
    const int tid = threadIdx.x;
    const int n0 = blockIdx.x * 64;
    const int m0 = blockIdx.y * 64;
    const int bidx = m0 >> 12;
    const int l0 = m0 & 4095;
    const int tx = tid & 15, ty = tid >> 4;
    float ax[4][4] = {}, ag[4][4] = {}, ae_[4][4] = {};
    const int kl = tid >> 4;        // 0..15
    const int mq = (tid & 15) * 4;  // A column (m) quad
    const size_t CL = 256 * 4096;

    for (int k0 = 0; k0 < 256; k0 += BK) {
        float4 vad = *(const float4*)&dec[(size_t)bidx * CL + (size_t)(k0 + kl) * 4096 + l0 + mq];
        float4 vae = *(const float4*)&enc[(size_t)bidx * CL + (size_t)(k0 + kl) * 4096 + l0 + mq];
        float4 vbx = *(const float4*)&dec_w[(size_t)(k0 + kl) * 1024 + n0 + mq];
        float4 vbg = *(const float4*)&dec_w[(size_t)(k0 + kl) * 1024 + 512 + n0 + mq];
        float4 vbe = *(const float4*)&enc_w[(size_t)(k0 + kl) * 512 + n0 + mq];
        *(float4*)&Ad[kl * LDT + mq] = vad;
        *(float4*)&Ae[kl * LDT + mq] = vae;
        *(float4*)&Bx[kl * LDT + mq] = vbx;
        *(float4*)&Bg[kl * LDT + mq] = vbg;
        *(float4*)&Be[kl * LDT + mq] = vbe;
        __syncthreads();
#pragma unroll
        for (int kk = 0; kk < BK; ++kk) {
            float4 a1 = *(const float4*)&Ad[kk * LDT + ty * 4];
            float4 a2 = *(const float4*)&Ae[kk * LDT + ty * 4];
            float4 b1 = *(const float4*)&Bx[kk * LDT + tx * 4];
            float4 b2 = *(const float4*)&Bg[kk * LDT + tx * 4];
            float4 b3 = *(const float4*)&Be[kk * LDT + tx * 4];
            float av1[4] = {a1.x, a1.y, a1.z, a1.w};
            float av2[4] = {a2.x, a2.y, a2.z, a2.w};
            float bx_[4] = {b1.x, b1.y, b1.z, b1.w};
            float bg_[4] = {b2.x, b2.y, b2.z, b2.w};
            float be2[4] = {b3.x, b3.y, b3.z, b3.w};
#pragma unroll
            for (int i = 0; i < 4; ++i)
#pragma unroll
                for (int j = 0; j < 4; ++j) {
                    ax[i][j] = fmaf(av1[i], bx_[j], ax[i][j]);
                    ag[i][j] = fmaf(av1[i], bg_[j], ag[i][j]);
                    ae_[i][j] = fmaf(av2[i], be2[j], ae_[i][j]);
                }
        }
        __syncthreads();
    }
#pragma unroll
    for (int i = 0; i < 4; ++i) {
        int m = m0 + ty * 4 + i;
#pragma unroll
        for (int j = 0; j < 4; ++j) {
            int n = n0 + tx * 4 + j;
            float dx = ax[i][j] + dec_b[n];
            float dg = ag[i][j] + dec_b[512 + n];
            float ep = ae_[i][j] + enc_b[n];
            combined[(size_t)m * 512 + n] = dx * sigmoidf_(ep) + ep;
            dec_gate[(size_t)m * 512 + n] = dg;
        }
    }
}

// ---------------------------------------------------------------------------
// Generic row-major SGEMM with compile-time epilogue.
// EPI 0: xz split     -> n<512: out0[m,n]=v ; n>=512: out1[m,n-512]=silu(v)
// EPI 1: mamba out    -> out0[m,n] = v * sigmoid(extra[m,n])   (extra=dec_gate)
// EPI 2: out proj     -> out0[m,n] = v + decoder_feat[b,n,l]   (extra=decoder)
// ---------------------------------------------------------------------------
template <int EPI>
__global__ __launch_bounds__(256) void sgemm_k(
    const float* __restrict__ A, const float* __restrict__ Bw,
    const float* __restrict__ bias, float* __restrict__ out0,
    float* __restrict__ out1, const float* __restrict__ extra,
    int M, int N, int K)
{
    __shared__ float As[BK * LDT];
    __shared__ float Bs[BK * LDT];
    const int tid = threadIdx.x;
    const int n0 = blockIdx.x * 64;
    const int m0 = blockIdx.y * 64;
    const int tx = tid & 15, ty = tid >> 4;
    float acc[4][4] = {};
    const int am = tid >> 2;         // 0..63 (m row)
    const int ak = (tid & 3) * 4;    // k quad
    const int bk = tid >> 4;         // 0..15 (k row)
    const int bn = (tid & 15) * 4;   // n quad

    for (int k0 = 0; k0 < K; k0 += BK) {
        float4 va = *(const float4*)&A[(size_t)(m0 + am) * K + k0 + ak];
        float4 vb = *(const float4*)&Bw[(size_t)(k0 + bk) * N + n0 + bn];
        As[(ak + 0) * LDT + am] = va.x;
        As[(ak + 1) * LDT + am] = va.y;
        As[(ak + 2) * LDT + am] = va.z;
        As[(ak + 3) * LDT + am] = va.w;
        *(float4*)&Bs[bk * LDT + bn] = vb;
        __syncthreads();
#pragma unroll
        for (int kk = 0; kk < BK; ++kk) {
            float4 a = *(const float4*)&As[kk * LDT + ty * 4];
            float4 b = *(const float4*)&Bs[kk * LDT + tx * 4];
            float av[4] = {a.x, a.y, a.z, a.w};
            float bv[4] = {b.x, b.y, b.z, b.w};
#pragma unroll
            for (int i = 0; i < 4; ++i)
#pragma unroll
                for (int j = 0; j < 4; ++j)
                    acc[i][j] = fmaf(av[i], bv[j], acc[i][j]);
        }
        __syncthreads();
    }
#pragma unroll
    for (int i = 0; i < 4; ++i) {
        int m = m0 + ty * 4 + i;
#pragma unroll
        for (int j = 0; j < 4; ++j) {
            int n = n0 + tx * 4 + j;
            float v = acc[i][j] + bias[n];
            if (EPI == 0) {
                if (n < 512) out0[(size_t)m * 512 + n] = v;
                else         out1[(size_t)m * 512 + (n - 512)] = siluf_(v);
            } else if (EPI == 1) {
                float g = extra[(size_t)m * 512 + n];
                out0[(size_t)m * 512 + n] = v * sigmoidf_(g);
            } else {
                int b = m >> 12, l = m & 4095;
                float dv = extra[(size_t)b * (256 * 4096) + (size_t)n * 4096 + l];
                out0[(size_t)m * 256 + n] = v + dv;
            }
        }
    }
}

// ---------------------------------------------------------------------------
// K3+K4: depthwise causal conv (K=4) + silu -> u ; x_dbl = u @ x_proj_w ;
//        dt = softplus(x_dbl[:, :32] @ dt_w + dt_b) ; store Bm, Cm.
// ---------------------------------------------------------------------------
__global__ __launch_bounds__(256) void k_conv_proj(
    const float* __restrict__ xm, const float* __restrict__ conv_w,
    const float* __restrict__ conv_b, const float* __restrict__ x_proj_w,
    const float* __restrict__ dt_w, const float* __restrict__ dt_b,
    float* __restrict__ u_out, float* __restrict__ Bm, float* __restrict__ Cm,
    float* __restrict__ dt_out)
{
    __shared__ float us[512];
    __shared__ float part[4][64];
    __shared__ float xd[64];
    const int tid = threadIdx.x;
    const int bl = blockIdx.x;
    const int l = bl & 4095;

#pragma unroll
    for (int dd = 0; dd < 2; ++dd) {
        int d = tid + dd * 256;
        float acc = conv_b[d];
#pragma unroll
        for (int k = 0; k < 4; ++k) {
            int ll = l - 3 + k;
            if (ll >= 0) acc = fmaf(conv_w[d * 4 + k], xm[(size_t)(bl - 3 + k) * 512 + d], acc);
        }
        float uv = siluf_(acc);
        us[d] = uv;
        u_out[(size_t)bl * 512 + d] = uv;
    }
    __syncthreads();

    {   // x_dbl: 64 outputs, 4 k-slices of 128 each
        int j = tid & 63;
        int s = tid >> 6;
        float p = 0.f;
        for (int k = s * 128; k < s * 128 + 128; ++k)
            p = fmaf(us[k], x_proj_w[(size_t)k * 64 + j], p);
        part[s][j] = p;
    }
    __syncthreads();
    if (tid < 64) {
        float v = part[0][tid] + part[1][tid] + part[2][tid] + part[3][tid];
        xd[tid] = v;
        if (tid >= 32 && tid < 48)      Bm[(size_t)bl * 16 + (tid - 32)] = v;
        else if (tid >= 48)             Cm[(size_t)bl * 16 + (tid - 48)] = v;
    }
    __syncthreads();

#pragma unroll
    for (int dd = 0; dd < 2; ++dd) {
        int d = tid + dd * 256;
        float a = dt_b[d];
#pragma unroll
        for (int r = 0; r < 32; ++r)
            a = fmaf(xd[r], dt_w[(size_t)r * 512 + d], a);
        dt_out[(size_t)bl * 512 + d] = softplusf_(a);
    }
}

// ---------------------------------------------------------------------------
// Chunked parallel scan. L=4096 split into 64 chunks of 64 steps.
// Chain per (b,d,n): h_t = exp(dt_t*A)*h_{t-1} + (dt*u)_t*B_t.
// Pass A: per (b,chunk,d,n) scan from h=0 -> partial P, decay D=exp(A*sum dt).
// Pass B: per (b,d,n) serial combine over 64 chunks -> h_in per chunk.
// Pass C: replay from h_in, 16-lane reduce for y, fuse (y+u*D)*silu(z).
// Scratch layout [b, chunk, d, n] is wave-coalesced in all passes.
// ---------------------------------------------------------------------------
#define CHUNK 64
#define NCHUNK 64

__global__ __launch_bounds__(256) void k_scan_part(
    const float* __restrict__ dt, const float* __restrict__ u,
    const float* __restrict__ Bmp, const float* __restrict__ A_log,
    float* __restrict__ hpart, float* __restrict__ decay)
{
    const int gid = blockIdx.x * 256 + threadIdx.x;
    const int n = gid & 15;
    const int d = (gid >> 4) & 511;
    const int chunk = (gid >> 13) & 63;
    const int b = gid >> 19;
    const float Av = -__expf(A_log[d * 16 + n]);
    const size_t row0 = (size_t)b * 4096 + (size_t)chunk * CHUNK;
    const float* dtp = dt + row0 * 512 + d;
    const float* up  = u  + row0 * 512 + d;
    const float* Bp  = Bmp + row0 * 16 + n;

    float h = 0.f, dtsum = 0.f;
#pragma unroll 4
    for (int t = 0; t < CHUNK; ++t) {
        float dtv = dtp[(size_t)t * 512];
        float uv  = up[(size_t)t * 512];
        float Bv  = Bp[(size_t)t * 16];
        dtsum += dtv;
        h = fmaf(h, __expf(dtv * Av), dtv * uv * Bv);
    }
    const size_t idx = (((size_t)b * NCHUNK + chunk) * 512 + d) * 16 + n;
    hpart[idx] = h;
    decay[idx] = __expf(Av * dtsum);
}

__global__ __launch_bounds__(256) void k_scan_comb(
    const float* __restrict__ hpart, const float* __restrict__ decay,
    float* __restrict__ h_in)
{
    const int gid = blockIdx.x * 256 + threadIdx.x;  // (b,d,n) = 16384 chains
    const int n = gid & 15;
    const int d = (gid >> 4) & 511;
    const int b = gid >> 13;
    float h = 0.f;
    for (int c = 0; c < NCHUNK; ++c) {
        const size_t idx = (((size_t)b * NCHUNK + c) * 512 + d) * 16 + n;
        h_in[idx] = h;
        h = fmaf(h, decay[idx], hpart[idx]);
    }
}

__global__ __launch_bounds__(256) void k_scan_fin(
    const float* __restrict__ dt, const float* __restrict__ u,
    const float* __restrict__ Bmp, const float* __restrict__ Cmp,
    const float* __restrict__ A_log, const float* __restrict__ Dp,
    const float* __restrict__ zs, const float* __restrict__ h_in,
    float* __restrict__ yout)
{
    const int gid = blockIdx.x * 256 + threadIdx.x;
    const int n = gid & 15;
    const int d = (gid >> 4) & 511;
    const int chunk = (gid >> 13) & 63;
    const int b = gid >> 19;
    const float Av = -__expf(A_log[d * 16 + n]);
    const float Dv = Dp[d];
    const size_t row0 = (size_t)b * 4096 + (size_t)chunk * CHUNK;
    const float* dtp = dt + row0 * 512 + d;
    const float* up  = u  + row0 * 512 + d;
    const float* Bp  = Bmp + row0 * 16 + n;
    const float* Cp  = Cmp + row0 * 16 + n;
    const float* zp  = zs + row0 * 512 + d;
    float* yp = yout + row0 * 512 + d;

    const size_t idx = (((size_t)b * NCHUNK + chunk) * 512 + d) * 16 + n;
    float h = h_in[idx];
#pragma unroll 4
    for (int t = 0; t < CHUNK; ++t) {
        float dtv = dtp[(size_t)t * 512];
        float uv  = up[(size_t)t * 512];
        float Bv  = Bp[(size_t)t * 16];
        float Cv  = Cp[(size_t)t * 16];
        h = fmaf(h, __expf(dtv * Av), dtv * uv * Bv);
        float y = h * Cv;
        y += __shfl_xor(y, 1);
        y += __shfl_xor(y, 2);
        y += __shfl_xor(y, 4);
        y += __shfl_xor(y, 8);
        if (n == 0) {
            yp[(size_t)t * 512] = (y + uv * Dv) * zp[(size_t)t * 512];
        }
    }
}

// ---------------------------------------------------------------------------
// K7b: LayerNorm over C=256 + transpose write to (B,C,H,W).
// ---------------------------------------------------------------------------
__global__ __launch_bounds__(256) void k_ln_t(
    const float* __restrict__ res, const float* __restrict__ ln_g,
    const float* __restrict__ ln_b, float* __restrict__ outp)
{
    __shared__ float r[64 * 257];
    __shared__ float red[64][8];
    __shared__ float mu_s[64], sc_s[64];
    const int tid = threadIdx.x;
    const int b = blockIdx.x >> 6;
    const int l0 = (blockIdx.x & 63) * 64;
    const size_t base = ((size_t)b * 4096 + l0) * 256;

    for (int e = tid; e < 64 * 256; e += 256) {
        int i = e >> 8;
        int c = e & 255;
        r[i * 257 + c] = res[base + (size_t)i * 256 + c];
    }
    __syncthreads();
    {
        int i = tid >> 2, s = tid & 3;
        float ps = 0.f, pq = 0.f;
        for (int c = s * 64; c < s * 64 + 64; ++c) {
            float v = r[i * 257 + c];
            ps += v;
            pq = fmaf(v, v, pq);
        }
        red[i][s] = ps;
        red[i][4 + s] = pq;
    }
    __syncthreads();
    if (tid < 64) {
        float ps = red[tid][0] + red[tid][1] + red[tid][2] + red[tid][3];
        float pq = red[tid][4] + red[tid][5] + red[tid][6] + red[tid][7];
        float mu = ps * (1.0f / 256.0f);
        float var = pq * (1.0f / 256.0f) - mu * mu;
        mu_s[tid] = mu;
        sc_s[tid] = rsqrtf(var + 1e-5f);
    }
    __syncthreads();
    const int il = tid & 63;
    const int cg = tid >> 6;
    const float mu = mu_s[il], sc = sc_s[il];
    for (int c = cg; c < 256; c += 4) {
        float v = (r[il * 257 + c] - mu) * sc * ln_g[c] + ln_b[c];
        outp[(size_t)b * (256 * 4096) + (size_t)c * 4096 + l0 + il] = v;
    }
}

// ---------------------------------------------------------------------------
extern "C" void kernel_launch(void* const* d_in, const int* in_sizes, int n_in,
                              void* d_out, int out_size, void* d_ws, size_t ws_size,
                              hipStream_t stream)
{
    const float* decoder_feat = (const float*)d_in[0];
    const float* encoder_feat = (const float*)d_in[1];
    const float* dec_w = (const float*)d_in[2];
    const float* dec_b = (const float*)d_in[3];
    const float* enc_w = (const float*)d_in[4];
    const float* enc_b = (const float*)d_in[5];
    const float* out_w = (const float*)d_in[6];
    const float* out_b = (const float*)d_in[7];
    const float* ln_g = (const float*)d_in[8];
    const float* ln_bb = (const float*)d_in[9];
    const float* in_w = (const float*)d_in[10];
    const float* in_b = (const float*)d_in[11];
    const float* conv_w = (const float*)d_in[12];
    const float* conv_b = (const float*)d_in[13];
    const float* x_proj_w = (const float*)d_in[14];
    const float* dt_w = (const float*)d_in[15];
    const float* dt_b = (const float*)d_in[16];
    const float* A_log = (const float*)d_in[17];
    const float* D_param = (const float*)d_in[18];
    const float* m_out_w = (const float*)d_in[19];
    const float* m_out_b = (const float*)d_in[20];

    float* outp = (float*)d_out;
    float* ws = (float*)d_ws;
    const size_t S = 8192ull * 512;  // 4M floats per slot
    float* combined = ws;            // slot0: combined, later y_final
    float* dec_gate = ws + S;        // slot1
    float* xm       = ws + 2 * S;    // slot2: xm; scan scratch; later gated
    float* z_silu   = ws + 3 * S;    // slot3
    float* u_buf    = ws + 4 * S;    // slot4
    float* dt_buf   = ws + 5 * S;    // slot5: dt, later res
    float* Bm       = ws + 6 * S;          // 131072 floats
    float* Cm       = ws + 6 * S + 131072; // 131072 floats

    // scan scratch reuses slot2 (xm is dead after k_conv_proj)
    const size_t SC = 2ull * NCHUNK * 512 * 16;  // 1M floats
    float* hpart = xm;
    float* decay = xm + SC;
    float* h_in  = xm + 2 * SC;

    // 1) input projections + cross gate
    k_fuse_in<<<dim3(8, 128), 256, 0, stream>>>(
        decoder_feat, encoder_feat, dec_w, dec_b, enc_w, enc_b, combined, dec_gate);
    // 2) xz = combined @ in_w -> xm, silu(z)
    sgemm_k<0><<<dim3(16, 128), 256, 0, stream>>>(
        combined, in_w, in_b, xm, z_silu, nullptr, 8192, 1024, 512);
    // 3) conv + silu -> u ; x_dbl ; dt ; Bm ; Cm
    k_conv_proj<<<8192, 256, 0, stream>>>(
        xm, conv_w, conv_b, x_proj_w, dt_w, dt_b, u_buf, Bm, Cm, dt_buf);
    // NOTE: hpart/decay/h_in alias xm — safe, k_conv_proj finished reading xm
    // 4a) chunk partials
    k_scan_part<<<4096, 256, 0, stream>>>(
        dt_buf, u_buf, Bm, A_log, hpart, decay);
    // 4b) cross-chunk combine
    k_scan_comb<<<64, 256, 0, stream>>>(hpart, decay, h_in);
    // 4c) replay + y + gate-by-silu(z) -> y_final (slot0)
    k_scan_fin<<<4096, 256, 0, stream>>>(
        dt_buf, u_buf, Bm, Cm, A_log, D_param, z_silu, h_in, combined);
    // 5) gated = (y @ m_out_w + b) * sigmoid(dec_gate)  (into slot2)
    sgemm_k<1><<<dim3(8, 128), 256, 0, stream>>>(
        combined, m_out_w, m_out_b, xm, nullptr, dec_gate, 8192, 512, 512);
    // 6) res = gated @ out_w + out_b + dec  (into slot5)
    sgemm_k<2><<<dim3(4, 128), 256, 0, stream>>>(
        xm, out_w, out_b, dt_buf, nullptr, decoder_feat, 8192, 256, 512);
    // 7) LayerNorm + transpose to (B,C,H,W)
    k_ln_t<<<128, 256, 0, stream>>>(dt_buf, ln_g, ln_bb, outp);
}

// Round 3
// 387.389 us; speedup vs baseline: 5.8756x; 1.5767x over previous
//
#include <hip/hip_runtime.h>
#include <hip/hip_bf16.h>

typedef __bf16 bf16x8_t __attribute__((ext_vector_type(8)));
typedef float f32x4_t __attribute__((ext_vector_type(4)));

__device__ __forceinline__ float sigmoidf_(float x) { return 1.0f / (1.0f + __expf(-x)); }
__device__ __forceinline__ float siluf_(float x) { return x * sigmoidf_(x); }
__device__ __forceinline__ float softplusf_(float x) {
    return fmaxf(x, 0.0f) + log1pf(__expf(-fabsf(x)));
}

// ---------------------------------------------------------------------------
// Cast + transpose all weight matrices fp32 [K][N] -> bf16 [N][K].
// Segments: dec_w(256x1024) enc_w(256x512) in_w(512x1024) m_out_w(512x512)
//           out_w(512x256). Total 1,310,720 elems = 5120 blocks x 256.
// ---------------------------------------------------------------------------
__global__ __launch_bounds__(256) void k_cast_w(
    const float* __restrict__ dec_w, const float* __restrict__ enc_w,
    const float* __restrict__ in_w, const float* __restrict__ m_out_w,
    const float* __restrict__ out_w,
    __hip_bfloat16* __restrict__ dec_wT, __hip_bfloat16* __restrict__ enc_wT,
    __hip_bfloat16* __restrict__ in_wT, __hip_bfloat16* __restrict__ m_out_wT,
    __hip_bfloat16* __restrict__ out_wT)
{
    int gid = blockIdx.x * 256 + threadIdx.x;
    const float* src; __hip_bfloat16* dst; int lk, N, idx;
    if (gid < 262144)       { src = dec_w;   dst = dec_wT;   lk = 8; N = 1024; idx = gid; }
    else if (gid < 393216)  { src = enc_w;   dst = enc_wT;   lk = 8; N = 512;  idx = gid - 262144; }
    else if (gid < 917504)  { src = in_w;    dst = in_wT;    lk = 9; N = 1024; idx = gid - 393216; }
    else if (gid < 1179648) { src = m_out_w; dst = m_out_wT; lk = 9; N = 512;  idx = gid - 917504; }
    else                    { src = out_w;   dst = out_wT;   lk = 9; N = 256;  idx = gid - 1179648; }
    int K = 1 << lk;
    int n = idx >> lk, k = idx & (K - 1);
    dst[idx] = __float2bfloat16(src[(size_t)k * N + n]);
}

// ---------------------------------------------------------------------------
// Transpose inputs (b,c,l) fp32 -> (b,l,c) bf16 for dec and enc.
// 64x64 LDS tile. grid = 4 c-tiles x 64 l-tiles x 4 (b x tensor).
// ---------------------------------------------------------------------------
__global__ __launch_bounds__(256) void k_tr_in(
    const float* __restrict__ dec, const float* __restrict__ enc,
    __hip_bfloat16* __restrict__ decL, __hip_bfloat16* __restrict__ encL)
{
    __shared__ float tile[64][65];
    const int t = threadIdx.x;
    const int ct = blockIdx.x & 3;
    const int lt = (blockIdx.x >> 2) & 63;
    const int sel = blockIdx.x >> 8;
    const int b = sel & 1, ten = sel >> 1;
    const float* src = ten ? enc : dec;
    __hip_bfloat16* dst = ten ? encL : decL;
    const size_t ibase = (size_t)b * 256 * 4096 + (size_t)(ct * 64) * 4096 + (size_t)lt * 64;
#pragma unroll
    for (int i = 0; i < 16; ++i) {
        int c = i * 4 + (t >> 6), l = t & 63;
        tile[c][l] = src[ibase + (size_t)c * 4096 + l];
    }
    __syncthreads();
    const size_t obase = ((size_t)b * 4096 + (size_t)lt * 64) * 256 + ct * 64;
#pragma unroll
    for (int i = 0; i < 16; ++i) {
        int l = i * 4 + (t >> 6), c = t & 63;
        dst[obase + (size_t)l * 256 + c] = __float2bfloat16(tile[c][l]);
    }
}

// ---------------------------------------------------------------------------
// bf16 MFMA GEMM: C[M][N] = A[M][K](bf16) @ Bt[N][K](bf16, pre-transposed).
// 128x128 block tile, BK=32, 4 waves each 64x64 (4x4 frags of 16x16x32).
// Fragment maps (m89/m92-verified): A lane holds A[m=lane&15][k=(lane>>4)*8+j];
// B lane holds B[k][n=lane&15] from [n][k] LDS; D: col=lane&15,row=(lane>>4)*4+r.
// EPI 0: enc_p fp32          out0=enc_p
// EPI 1: combined/gate       out0=combined bf16 (n<512, extra=enc_p), out1=gate f32
// EPI 2: xz split            out0=xm bf16 (n<512), out1=silu(z) bf16
// EPI 3: * sigmoid(gate)     out0=gated bf16, extra=dec_gate f32
// EPI 4: + residual          out0=res f32, extra=decL bf16 [m][256]
// ---------------------------------------------------------------------------
template <int EPI, int K>
__global__ __launch_bounds__(256) void bgemm(
    const __hip_bfloat16* __restrict__ A, const __hip_bfloat16* __restrict__ Bt,
    const float* __restrict__ bias, void* __restrict__ out0,
    void* __restrict__ out1, const void* __restrict__ extra)
{
    __shared__ ushort At[128 * 32];
    __shared__ ushort Bl[128 * 32];
    const int tid = threadIdx.x;
    const int wave = tid >> 6, lane = tid & 63;
    const int n0 = blockIdx.x * 128, m0 = blockIdx.y * 128;
    const int wm = (wave >> 1) * 64, wn = (wave & 1) * 64;
    f32x4_t acc[4][4] = {};
    const int fr = lane & 15, fq = (lane >> 4) * 8;

    for (int k0 = 0; k0 < K; k0 += 32) {
#pragma unroll
        for (int q = 0; q < 2; ++q) {
            int idx = q * 256 + tid;
            int row = idx >> 2, ch = (idx & 3) * 8;
            uint4 va = *(const uint4*)&A[(size_t)(m0 + row) * K + k0 + ch];
            uint4 vb = *(const uint4*)&Bt[(size_t)(n0 + row) * K + k0 + ch];
            *(uint4*)&At[row * 32 + ch] = va;
            *(uint4*)&Bl[row * 32 + ch] = vb;
        }
        __syncthreads();
        bf16x8_t af[4], bf[4];
#pragma unroll
        for (int i = 0; i < 4; ++i) {
            af[i] = *(bf16x8_t*)&At[(wm + i * 16 + fr) * 32 + fq];
            bf[i] = *(bf16x8_t*)&Bl[(wn + i * 16 + fr) * 32 + fq];
        }
#pragma unroll
        for (int i = 0; i < 4; ++i)
#pragma unroll
            for (int j = 0; j < 4; ++j)
                acc[i][j] = __builtin_amdgcn_mfma_f32_16x16x32_bf16(af[i], bf[j], acc[i][j], 0, 0, 0);
        __syncthreads();
    }

    const int col = lane & 15, rbase = (lane >> 4) * 4;
#pragma unroll
    for (int i = 0; i < 4; ++i) {
#pragma unroll
        for (int j = 0; j < 4; ++j) {
#pragma unroll
            for (int r = 0; r < 4; ++r) {
                int m = m0 + wm + i * 16 + rbase + r;
                int n = n0 + wn + j * 16 + col;
                float v = acc[i][j][r] + bias[n];
                if (EPI == 0) {
                    ((float*)out0)[(size_t)m * 512 + n] = v;
                } else if (EPI == 1) {
                    if (n < 512) {
                        float ep = ((const float*)extra)[(size_t)m * 512 + n];
                        ((__hip_bfloat16*)out0)[(size_t)m * 512 + n] =
                            __float2bfloat16(fmaf(v, sigmoidf_(ep), ep));
                    } else {
                        ((float*)out1)[(size_t)m * 512 + (n - 512)] = v;
                    }
                } else if (EPI == 2) {
                    if (n < 512)
                        ((__hip_bfloat16*)out0)[(size_t)m * 512 + n] = __float2bfloat16(v);
                    else
                        ((__hip_bfloat16*)out1)[(size_t)m * 512 + (n - 512)] =
                            __float2bfloat16(siluf_(v));
                } else if (EPI == 3) {
                    float g = ((const float*)extra)[(size_t)m * 512 + n];
                    ((__hip_bfloat16*)out0)[(size_t)m * 512 + n] =
                        __float2bfloat16(v * sigmoidf_(g));
                } else {
                    float dv = __bfloat162float(((const __hip_bfloat16*)extra)[(size_t)m * 256 + n]);
                    ((float*)out0)[(size_t)m * 256 + n] = v + dv;
                }
            }
        }
    }
}

// ---------------------------------------------------------------------------
// Depthwise causal conv(K=4)+silu -> u ; x_dbl = u @ x_proj_w ; dt ; Bm ; Cm.
// 4 rows per block (weights streamed once per 4 rows).
// ---------------------------------------------------------------------------
__global__ __launch_bounds__(256) void k_conv_proj(
    const __hip_bfloat16* __restrict__ xm, const float* __restrict__ conv_w,
    const float* __restrict__ conv_b, const float* __restrict__ x_proj_w,
    const float* __restrict__ dt_w, const float* __restrict__ dt_b,
    __hip_bfloat16* __restrict__ u_out, float* __restrict__ Bm,
    float* __restrict__ Cm, float* __restrict__ dt_out)
{
    __shared__ float us[4][512];
    __shared__ float part[4][4][64];
    __shared__ float xd[4][64];
    const int tid = threadIdx.x;
    const int bl0 = blockIdx.x * 4;
    const int l0 = bl0 & 4095;

#pragma unroll
    for (int dd = 0; dd < 2; ++dd) {
        int d = tid + dd * 256;
        float cw0 = conv_w[d * 4], cw1 = conv_w[d * 4 + 1];
        float cw2 = conv_w[d * 4 + 2], cw3 = conv_w[d * 4 + 3];
        float cb = conv_b[d];
        float x[7];
#pragma unroll
        for (int i = 0; i < 7; ++i) {
            int l = l0 - 3 + i;
            x[i] = (l >= 0) ? __bfloat162float(xm[(size_t)(bl0 - 3 + i) * 512 + d]) : 0.f;
        }
#pragma unroll
        for (int r = 0; r < 4; ++r) {
            float a = cb;
            a = fmaf(cw0, x[r], a);
            a = fmaf(cw1, x[r + 1], a);
            a = fmaf(cw2, x[r + 2], a);
            a = fmaf(cw3, x[r + 3], a);
            float uv = siluf_(a);
            us[r][d] = uv;
            u_out[(size_t)(bl0 + r) * 512 + d] = __float2bfloat16(uv);
        }
    }
    __syncthreads();
    {
        int j = tid & 63, s = tid >> 6;
        float p0 = 0, p1 = 0, p2 = 0, p3 = 0;
        for (int k = s * 128; k < s * 128 + 128; ++k) {
            float w = x_proj_w[(size_t)k * 64 + j];
            p0 = fmaf(us[0][k], w, p0);
            p1 = fmaf(us[1][k], w, p1);
            p2 = fmaf(us[2][k], w, p2);
            p3 = fmaf(us[3][k], w, p3);
        }
        part[s][0][j] = p0; part[s][1][j] = p1; part[s][2][j] = p2; part[s][3][j] = p3;
    }
    __syncthreads();
    {
        int r = tid >> 6, j = tid & 63;
        float v = part[0][r][j] + part[1][r][j] + part[2][r][j] + part[3][r][j];
        xd[r][j] = v;
        if (j >= 32 && j < 48)  Bm[(size_t)(bl0 + r) * 16 + (j - 32)] = v;
        else if (j >= 48)       Cm[(size_t)(bl0 + r) * 16 + (j - 48)] = v;
    }
    __syncthreads();
#pragma unroll
    for (int dd = 0; dd < 2; ++dd) {
        int d = tid + dd * 256;
        float a0 = dt_b[d], a1 = a0, a2 = a0, a3 = a0;
#pragma unroll
        for (int rr = 0; rr < 32; ++rr) {
            float w = dt_w[(size_t)rr * 512 + d];
            a0 = fmaf(xd[0][rr], w, a0);
            a1 = fmaf(xd[1][rr], w, a1);
            a2 = fmaf(xd[2][rr], w, a2);
            a3 = fmaf(xd[3][rr], w, a3);
        }
        dt_out[(size_t)(bl0 + 0) * 512 + d] = softplusf_(a0);
        dt_out[(size_t)(bl0 + 1) * 512 + d] = softplusf_(a1);
        dt_out[(size_t)(bl0 + 2) * 512 + d] = softplusf_(a2);
        dt_out[(size_t)(bl0 + 3) * 512 + d] = softplusf_(a3);
    }
}

// ---------------------------------------------------------------------------
// Chunked parallel scan (64 chunks x 64 steps), scratch [b,chunk,d,n].
// ---------------------------------------------------------------------------
#define CHUNK 64
#define NCHUNK 64

__global__ __launch_bounds__(256) void k_scan_part(
    const float* __restrict__ dt, const __hip_bfloat16* __restrict__ u,
    const float* __restrict__ Bmp, const float* __restrict__ A_log,
    float* __restrict__ hpart, float* __restrict__ decay)
{
    const int gid = blockIdx.x * 256 + threadIdx.x;
    const int n = gid & 15;
    const int d = (gid >> 4) & 511;
    const int chunk = (gid >> 13) & 63;
    const int b = gid >> 19;
    const float Av = -__expf(A_log[d * 16 + n]);
    const size_t row0 = (size_t)b * 4096 + (size_t)chunk * CHUNK;
    const float* dtp = dt + row0 * 512 + d;
    const __hip_bfloat16* up = u + row0 * 512 + d;
    const float* Bp = Bmp + row0 * 16 + n;

    float h = 0.f, dtsum = 0.f;
#pragma unroll 4
    for (int t = 0; t < CHUNK; ++t) {
        float dtv = dtp[(size_t)t * 512];
        float uv = __bfloat162float(up[(size_t)t * 512]);
        float Bv = Bp[(size_t)t * 16];
        dtsum += dtv;
        h = fmaf(h, __expf(dtv * Av), dtv * uv * Bv);
    }
    const size_t idx = (((size_t)b * NCHUNK + chunk) * 512 + d) * 16 + n;
    hpart[idx] = h;
    decay[idx] = __expf(Av * dtsum);
}

__global__ __launch_bounds__(256) void k_scan_comb(
    const float* __restrict__ hpart, const float* __restrict__ decay,
    float* __restrict__ h_in)
{
    const int gid = blockIdx.x * 256 + threadIdx.x;
    const int n = gid & 15;
    const int d = (gid >> 4) & 511;
    const int b = gid >> 13;
    float h = 0.f;
    for (int c = 0; c < NCHUNK; ++c) {
        const size_t idx = (((size_t)b * NCHUNK + c) * 512 + d) * 16 + n;
        h_in[idx] = h;
        h = fmaf(h, decay[idx], hpart[idx]);
    }
}

__global__ __launch_bounds__(256) void k_scan_fin(
    const float* __restrict__ dt, const __hip_bfloat16* __restrict__ u,
    const float* __restrict__ Bmp, const float* __restrict__ Cmp,
    const float* __restrict__ A_log, const float* __restrict__ Dp,
    const __hip_bfloat16* __restrict__ zs, const float* __restrict__ h_in,
    __hip_bfloat16* __restrict__ yout)
{
    const int gid = blockIdx.x * 256 + threadIdx.x;
    const int n = gid & 15;
    const int d = (gid >> 4) & 511;
    const int chunk = (gid >> 13) & 63;
    const int b = gid >> 19;
    const float Av = -__expf(A_log[d * 16 + n]);
    const float Dv = Dp[d];
    const size_t row0 = (size_t)b * 4096 + (size_t)chunk * CHUNK;
    const float* dtp = dt + row0 * 512 + d;
    const __hip_bfloat16* up = u + row0 * 512 + d;
    const float* Bp = Bmp + row0 * 16 + n;
    const float* Cp = Cmp + row0 * 16 + n;
    const __hip_bfloat16* zp = zs + row0 * 512 + d;
    __hip_bfloat16* yp = yout + row0 * 512 + d;

    const size_t idx = (((size_t)b * NCHUNK + chunk) * 512 + d) * 16 + n;
    float h = h_in[idx];
#pragma unroll 4
    for (int t = 0; t < CHUNK; ++t) {
        float dtv = dtp[(size_t)t * 512];
        float uv = __bfloat162float(up[(size_t)t * 512]);
        float Bv = Bp[(size_t)t * 16];
        float Cv = Cp[(size_t)t * 16];
        h = fmaf(h, __expf(dtv * Av), dtv * uv * Bv);
        float y = h * Cv;
        y += __shfl_xor(y, 1);
        y += __shfl_xor(y, 2);
        y += __shfl_xor(y, 4);
        y += __shfl_xor(y, 8);
        if (n == 0) {
            float zv = __bfloat162float(zp[(size_t)t * 512]);
            yp[(size_t)t * 512] = __float2bfloat16((y + uv * Dv) * zv);
        }
    }
}

// ---------------------------------------------------------------------------
// LayerNorm over C=256 + transposed write to (B,C,H,W).
// ---------------------------------------------------------------------------
__global__ __launch_bounds__(256) void k_ln_t(
    const float* __restrict__ res, const float* __restrict__ ln_g,
    const float* __restrict__ ln_b, float* __restrict__ outp)
{
    __shared__ float r[64 * 257];
    __shared__ float red[64][8];
    __shared__ float mu_s[64], sc_s[64];
    const int tid = threadIdx.x;
    const int b = blockIdx.x >> 6;
    const int l0 = (blockIdx.x & 63) * 64;
    const size_t base = ((size_t)b * 4096 + l0) * 256;

    for (int e = tid; e < 64 * 256; e += 256) {
        int i = e >> 8;
        int c = e & 255;
        r[i * 257 + c] = res[base + (size_t)i * 256 + c];
    }
    __syncthreads();
    {
        int i = tid >> 2, s = tid & 3;
        float ps = 0.f, pq = 0.f;
        for (int c = s * 64; c < s * 64 + 64; ++c) {
            float v = r[i * 257 + c];
            ps += v;
            pq = fmaf(v, v, pq);
        }
        red[i][s] = ps;
        red[i][4 + s] = pq;
    }
    __syncthreads();
    if (tid < 64) {
        float ps = red[tid][0] + red[tid][1] + red[tid][2] + red[tid][3];
        float pq = red[tid][4] + red[tid][5] + red[tid][6] + red[tid][7];
        float mu = ps * (1.0f / 256.0f);
        float var = pq * (1.0f / 256.0f) - mu * mu;
        mu_s[tid] = mu;
        sc_s[tid] = rsqrtf(var + 1e-5f);
    }
    __syncthreads();
    const int il = tid & 63;
    const int cg = tid >> 6;
    const float mu = mu_s[il], sc = sc_s[il];
    for (int c = cg; c < 256; c += 4) {
        float v = (r[il * 257 + c] - mu) * sc * ln_g[c] + ln_b[c];
        outp[(size_t)b * (256 * 4096) + (size_t)c * 4096 + l0 + il] = v;
    }
}

// ---------------------------------------------------------------------------
extern "C" void kernel_launch(void* const* d_in, const int* in_sizes, int n_in,
                              void* d_out, int out_size, void* d_ws, size_t ws_size,
                              hipStream_t stream)
{
    const float* decoder_feat = (const float*)d_in[0];
    const float* encoder_feat = (const float*)d_in[1];
    const float* dec_w = (const float*)d_in[2];
    const float* dec_b = (const float*)d_in[3];
    const float* enc_w = (const float*)d_in[4];
    const float* enc_b = (const float*)d_in[5];
    const float* out_w = (const float*)d_in[6];
    const float* out_b = (const float*)d_in[7];
    const float* ln_g = (const float*)d_in[8];
    const float* ln_bb = (const float*)d_in[9];
    const float* in_w = (const float*)d_in[10];
    const float* in_b = (const float*)d_in[11];
    const float* conv_w = (const float*)d_in[12];
    const float* conv_b = (const float*)d_in[13];
    const float* x_proj_w = (const float*)d_in[14];
    const float* dt_w = (const float*)d_in[15];
    const float* dt_b = (const float*)d_in[16];
    const float* A_log = (const float*)d_in[17];
    const float* D_param = (const float*)d_in[18];
    const float* m_out_w = (const float*)d_in[19];
    const float* m_out_b = (const float*)d_in[20];

    float* outp = (float*)d_out;
    char* ws = (char*)d_ws;
    const size_t MB = 1024ull * 1024;
    // bf16 buffers
    __hip_bfloat16* decL     = (__hip_bfloat16*)(ws + 0 * MB);    // 4 MB  [8192][256]
    __hip_bfloat16* encL     = (__hip_bfloat16*)(ws + 4 * MB);    // 4 MB
    __hip_bfloat16* dec_wT   = (__hip_bfloat16*)(ws + 8 * MB);    // 0.5 MB [1024][256]
    __hip_bfloat16* enc_wT   = (__hip_bfloat16*)(ws + 9 * MB);    // 0.25   [512][256]
    __hip_bfloat16* in_wT    = (__hip_bfloat16*)(ws + 10 * MB);   // 1 MB   [1024][512]
    __hip_bfloat16* m_out_wT = (__hip_bfloat16*)(ws + 11 * MB);   // 0.5    [512][512]
    __hip_bfloat16* out_wT   = (__hip_bfloat16*)(ws + 12 * MB);   // 0.25   [256][512]
    float* enc_p   = (float*)(ws + 13 * MB);                      // 16 MB; reused: scan scratch
    __hip_bfloat16* combined = (__hip_bfloat16*)(ws + 29 * MB);   // 8 MB; reused: y
    float* dec_gate = (float*)(ws + 37 * MB);                     // 16 MB
    __hip_bfloat16* xm = (__hip_bfloat16*)(ws + 53 * MB);         // 8 MB; reused: gated
    __hip_bfloat16* z_silu = (__hip_bfloat16*)(ws + 61 * MB);     // 8 MB
    __hip_bfloat16* u_buf = (__hip_bfloat16*)(ws + 69 * MB);      // 8 MB
    float* dt_buf = (float*)(ws + 77 * MB);                       // 16 MB; reused: res (8 MB)
    float* Bm = (float*)(ws + 93 * MB);                           // 0.5 MB
    float* Cm = (float*)(ws + 93 * MB + 524288);                  // 0.5 MB
    // aliases (dead-slot reuse; safe: producer launches strictly after last reader)
    float* hpart = enc_p;                                          // 4 MB
    float* decay = enc_p + 1048576;                                // 4 MB
    float* h_in  = enc_p + 2097152;                                // 4 MB
    __hip_bfloat16* y_buf = combined;
    __hip_bfloat16* gated = xm;
    float* res = dt_buf;

    // 0) weight cast+transpose, input transpose
    k_cast_w<<<5120, 256, 0, stream>>>(dec_w, enc_w, in_w, m_out_w, out_w,
                                       dec_wT, enc_wT, in_wT, m_out_wT, out_wT);
    k_tr_in<<<1024, 256, 0, stream>>>(decoder_feat, encoder_feat, decL, encL);
    // 1) enc_p = encL @ enc_w + enc_b (fp32)
    bgemm<0, 256><<<dim3(4, 64), 256, 0, stream>>>(
        encL, enc_wT, enc_b, enc_p, nullptr, nullptr);
    // 2) dec proj -> combined bf16 (cross-gate fused), dec_gate fp32
    bgemm<1, 256><<<dim3(8, 64), 256, 0, stream>>>(
        decL, dec_wT, dec_b, combined, dec_gate, enc_p);
    // 3) xz = combined @ in_w -> xm bf16, silu(z) bf16
    bgemm<2, 512><<<dim3(8, 64), 256, 0, stream>>>(
        combined, in_wT, in_b, xm, z_silu, nullptr);
    // 4) conv + silu -> u ; x_dbl ; dt ; Bm ; Cm
    k_conv_proj<<<2048, 256, 0, stream>>>(
        xm, conv_w, conv_b, x_proj_w, dt_w, dt_b, u_buf, Bm, Cm, dt_buf);
    // 5) scan (chunked): part -> comb -> fin (y bf16, gated by silu(z))
    k_scan_part<<<4096, 256, 0, stream>>>(dt_buf, u_buf, Bm, A_log, hpart, decay);
    k_scan_comb<<<64, 256, 0, stream>>>(hpart, decay, h_in);
    k_scan_fin<<<4096, 256, 0, stream>>>(
        dt_buf, u_buf, Bm, Cm, A_log, D_param, z_silu, h_in, y_buf);
    // 6) gated = (y @ m_out_w + b) * sigmoid(dec_gate)
    bgemm<3, 512><<<dim3(4, 64), 256, 0, stream>>>(
        y_buf, m_out_wT, m_out_b, gated, nullptr, dec_gate);
    // 7) res = gated @ out_w + out_b + dec (fp32)
    bgemm<4, 512><<<dim3(2, 64), 256, 0, stream>>>(
        gated, out_wT, out_b, res, nullptr, decL);
    // 8) LayerNorm + transpose out
    k_ln_t<<<128, 256, 0, stream>>>(res, ln_g, ln_bb, outp);
}

// Round 4
// 312.772 us; speedup vs baseline: 7.2773x; 1.2386x over previous
//
#include <hip/hip_runtime.h>
#include <hip/hip_bf16.h>

typedef __bf16 bf16x8_t __attribute__((ext_vector_type(8)));
typedef float f32x4_t __attribute__((ext_vector_type(4)));

__device__ __forceinline__ float sigmoidf_(float x) { return 1.0f / (1.0f + __expf(-x)); }
__device__ __forceinline__ float siluf_(float x) { return x * sigmoidf_(x); }
__device__ __forceinline__ float softplusf_(float x) {
    return fmaxf(x, 0.0f) + log1pf(__expf(-fabsf(x)));
}

// ---------------------------------------------------------------------------
// Cast + transpose all weight matrices fp32 [K][N] -> bf16 [N][K].
// ---------------------------------------------------------------------------
__global__ __launch_bounds__(256) void k_cast_w(
    const float* __restrict__ dec_w, const float* __restrict__ enc_w,
    const float* __restrict__ in_w, const float* __restrict__ m_out_w,
    const float* __restrict__ out_w,
    __hip_bfloat16* __restrict__ dec_wT, __hip_bfloat16* __restrict__ enc_wT,
    __hip_bfloat16* __restrict__ in_wT, __hip_bfloat16* __restrict__ m_out_wT,
    __hip_bfloat16* __restrict__ out_wT)
{
    int gid = blockIdx.x * 256 + threadIdx.x;
    const float* src; __hip_bfloat16* dst; int lk, N, idx;
    if (gid < 262144)       { src = dec_w;   dst = dec_wT;   lk = 8; N = 1024; idx = gid; }
    else if (gid < 393216)  { src = enc_w;   dst = enc_wT;   lk = 8; N = 512;  idx = gid - 262144; }
    else if (gid < 917504)  { src = in_w;    dst = in_wT;    lk = 9; N = 1024; idx = gid - 393216; }
    else if (gid < 1179648) { src = m_out_w; dst = m_out_wT; lk = 9; N = 512;  idx = gid - 917504; }
    else                    { src = out_w;   dst = out_wT;   lk = 9; N = 256;  idx = gid - 1179648; }
    int K = 1 << lk;
    int n = idx >> lk, k = idx & (K - 1);
    dst[idx] = __float2bfloat16(src[(size_t)k * N + n]);
}

// ---------------------------------------------------------------------------
// Transpose inputs (b,c,l) fp32 -> (b,l,c) bf16 for dec and enc.
// ---------------------------------------------------------------------------
__global__ __launch_bounds__(256) void k_tr_in(
    const float* __restrict__ dec, const float* __restrict__ enc,
    __hip_bfloat16* __restrict__ decL, __hip_bfloat16* __restrict__ encL)
{
    __shared__ float tile[64][65];
    const int t = threadIdx.x;
    const int ct = blockIdx.x & 3;
    const int lt = (blockIdx.x >> 2) & 63;
    const int sel = blockIdx.x >> 8;
    const int b = sel & 1, ten = sel >> 1;
    const float* src = ten ? enc : dec;
    __hip_bfloat16* dst = ten ? encL : decL;
    const size_t ibase = (size_t)b * 256 * 4096 + (size_t)(ct * 64) * 4096 + (size_t)lt * 64;
#pragma unroll
    for (int i = 0; i < 16; ++i) {
        int c = i * 4 + (t >> 6), l = t & 63;
        tile[c][l] = src[ibase + (size_t)c * 4096 + l];
    }
    __syncthreads();
    const size_t obase = ((size_t)b * 4096 + (size_t)lt * 64) * 256 + ct * 64;
#pragma unroll
    for (int i = 0; i < 16; ++i) {
        int l = i * 4 + (t >> 6), c = t & 63;
        dst[obase + (size_t)l * 256 + c] = __float2bfloat16(tile[c][l]);
    }
}

// ---------------------------------------------------------------------------
// bf16 MFMA GEMM (128x128 tile, BK=32, 4 waves of 64x64).
// EPI 0: enc_p fp32 | EPI 1: combined bf16 + gate f32 | EPI 2: xm/silu(z) bf16
// EPI 3: * sigmoid(gate) bf16 | EPI 4: + residual f32
// ---------------------------------------------------------------------------
template <int EPI, int K>
__global__ __launch_bounds__(256) void bgemm(
    const __hip_bfloat16* __restrict__ A, const __hip_bfloat16* __restrict__ Bt,
    const float* __restrict__ bias, void* __restrict__ out0,
    void* __restrict__ out1, const void* __restrict__ extra)
{
    __shared__ ushort At[128 * 32];
    __shared__ ushort Bl[128 * 32];
    const int tid = threadIdx.x;
    const int wave = tid >> 6, lane = tid & 63;
    const int n0 = blockIdx.x * 128, m0 = blockIdx.y * 128;
    const int wm = (wave >> 1) * 64, wn = (wave & 1) * 64;
    f32x4_t acc[4][4] = {};
    const int fr = lane & 15, fq = (lane >> 4) * 8;

    for (int k0 = 0; k0 < K; k0 += 32) {
#pragma unroll
        for (int q = 0; q < 2; ++q) {
            int idx = q * 256 + tid;
            int row = idx >> 2, ch = (idx & 3) * 8;
            uint4 va = *(const uint4*)&A[(size_t)(m0 + row) * K + k0 + ch];
            uint4 vb = *(const uint4*)&Bt[(size_t)(n0 + row) * K + k0 + ch];
            *(uint4*)&At[row * 32 + ch] = va;
            *(uint4*)&Bl[row * 32 + ch] = vb;
        }
        __syncthreads();
        bf16x8_t af[4], bf[4];
#pragma unroll
        for (int i = 0; i < 4; ++i) {
            af[i] = *(bf16x8_t*)&At[(wm + i * 16 + fr) * 32 + fq];
            bf[i] = *(bf16x8_t*)&Bl[(wn + i * 16 + fr) * 32 + fq];
        }
#pragma unroll
        for (int i = 0; i < 4; ++i)
#pragma unroll
            for (int j = 0; j < 4; ++j)
                acc[i][j] = __builtin_amdgcn_mfma_f32_16x16x32_bf16(af[i], bf[j], acc[i][j], 0, 0, 0);
        __syncthreads();
    }

    const int col = lane & 15, rbase = (lane >> 4) * 4;
#pragma unroll
    for (int i = 0; i < 4; ++i) {
#pragma unroll
        for (int j = 0; j < 4; ++j) {
#pragma unroll
            for (int r = 0; r < 4; ++r) {
                int m = m0 + wm + i * 16 + rbase + r;
                int n = n0 + wn + j * 16 + col;
                float v = acc[i][j][r] + bias[n];
                if (EPI == 0) {
                    ((float*)out0)[(size_t)m * 512 + n] = v;
                } else if (EPI == 1) {
                    if (n < 512) {
                        float ep = ((const float*)extra)[(size_t)m * 512 + n];
                        ((__hip_bfloat16*)out0)[(size_t)m * 512 + n] =
                            __float2bfloat16(fmaf(v, sigmoidf_(ep), ep));
                    } else {
                        ((float*)out1)[(size_t)m * 512 + (n - 512)] = v;
                    }
                } else if (EPI == 2) {
                    if (n < 512)
                        ((__hip_bfloat16*)out0)[(size_t)m * 512 + n] = __float2bfloat16(v);
                    else
                        ((__hip_bfloat16*)out1)[(size_t)m * 512 + (n - 512)] =
                            __float2bfloat16(siluf_(v));
                } else if (EPI == 3) {
                    float g = ((const float*)extra)[(size_t)m * 512 + n];
                    ((__hip_bfloat16*)out0)[(size_t)m * 512 + n] =
                        __float2bfloat16(v * sigmoidf_(g));
                } else {
                    float dv = __bfloat162float(((const __hip_bfloat16*)extra)[(size_t)m * 256 + n]);
                    ((float*)out0)[(size_t)m * 256 + n] = v + dv;
                }
            }
        }
    }
}

// ---------------------------------------------------------------------------
// Depthwise causal conv(K=4)+silu -> u ; x_dbl = u @ x_proj_w ; dt ; Bm ; Cm.
// ---------------------------------------------------------------------------
__global__ __launch_bounds__(256) void k_conv_proj(
    const __hip_bfloat16* __restrict__ xm, const float* __restrict__ conv_w,
    const float* __restrict__ conv_b, const float* __restrict__ x_proj_w,
    const float* __restrict__ dt_w, const float* __restrict__ dt_b,
    __hip_bfloat16* __restrict__ u_out, float* __restrict__ Bm,
    float* __restrict__ Cm, float* __restrict__ dt_out)
{
    __shared__ float us[4][512];
    __shared__ float part[4][4][64];
    __shared__ float xd[4][64];
    const int tid = threadIdx.x;
    const int bl0 = blockIdx.x * 4;
    const int l0 = bl0 & 4095;

#pragma unroll
    for (int dd = 0; dd < 2; ++dd) {
        int d = tid + dd * 256;
        float cw0 = conv_w[d * 4], cw1 = conv_w[d * 4 + 1];
        float cw2 = conv_w[d * 4 + 2], cw3 = conv_w[d * 4 + 3];
        float cb = conv_b[d];
        float x[7];
#pragma unroll
        for (int i = 0; i < 7; ++i) {
            int l = l0 - 3 + i;
            x[i] = (l >= 0) ? __bfloat162float(xm[(size_t)(bl0 - 3 + i) * 512 + d]) : 0.f;
        }
#pragma unroll
        for (int r = 0; r < 4; ++r) {
            float a = cb;
            a = fmaf(cw0, x[r], a);
            a = fmaf(cw1, x[r + 1], a);
            a = fmaf(cw2, x[r + 2], a);
            a = fmaf(cw3, x[r + 3], a);
            float uv = siluf_(a);
            us[r][d] = uv;
            u_out[(size_t)(bl0 + r) * 512 + d] = __float2bfloat16(uv);
        }
    }
    __syncthreads();
    {
        int j = tid & 63, s = tid >> 6;
        float p0 = 0, p1 = 0, p2 = 0, p3 = 0;
        for (int k = s * 128; k < s * 128 + 128; ++k) {
            float w = x_proj_w[(size_t)k * 64 + j];
            p0 = fmaf(us[0][k], w, p0);
            p1 = fmaf(us[1][k], w, p1);
            p2 = fmaf(us[2][k], w, p2);
            p3 = fmaf(us[3][k], w, p3);
        }
        part[s][0][j] = p0; part[s][1][j] = p1; part[s][2][j] = p2; part[s][3][j] = p3;
    }
    __syncthreads();
    {
        int r = tid >> 6, j = tid & 63;
        float v = part[0][r][j] + part[1][r][j] + part[2][r][j] + part[3][r][j];
        xd[r][j] = v;
        if (j >= 32 && j < 48)  Bm[(size_t)(bl0 + r) * 16 + (j - 32)] = v;
        else if (j >= 48)       Cm[(size_t)(bl0 + r) * 16 + (j - 48)] = v;
    }
    __syncthreads();
#pragma unroll
    for (int dd = 0; dd < 2; ++dd) {
        int d = tid + dd * 256;
        float a0 = dt_b[d], a1 = a0, a2 = a0, a3 = a0;
#pragma unroll
        for (int rr = 0; rr < 32; ++rr) {
            float w = dt_w[(size_t)rr * 512 + d];
            a0 = fmaf(xd[0][rr], w, a0);
            a1 = fmaf(xd[1][rr], w, a1);
            a2 = fmaf(xd[2][rr], w, a2);
            a3 = fmaf(xd[3][rr], w, a3);
        }
        dt_out[(size_t)(bl0 + 0) * 512 + d] = softplusf_(a0);
        dt_out[(size_t)(bl0 + 1) * 512 + d] = softplusf_(a1);
        dt_out[(size_t)(bl0 + 2) * 512 + d] = softplusf_(a2);
        dt_out[(size_t)(bl0 + 3) * 512 + d] = softplusf_(a3);
    }
}

// ---------------------------------------------------------------------------
// Chunked parallel scan, thread-per-(b,chunk,d), N=16 state in registers.
// CHUNK=32, NCHUNK=128. B/C chunk staged in LDS (broadcast reads).
// Scratch layout [b,chunk,d,n] -> 16 contiguous floats per thread.
// ---------------------------------------------------------------------------
#define CHUNK 32
#define NCHUNK 128

__global__ __launch_bounds__(512) void k_scan_part(
    const float* __restrict__ dt, const __hip_bfloat16* __restrict__ u,
    const float* __restrict__ Bmp, const float* __restrict__ A_log,
    float* __restrict__ hpart, float* __restrict__ decay)
{
    __shared__ float Bs[CHUNK * 16];
    const int d = threadIdx.x;                  // 0..511
    const int chunk = blockIdx.x & (NCHUNK - 1);
    const int b = blockIdx.x >> 7;
    const size_t row0 = (size_t)b * 4096 + (size_t)chunk * CHUNK;

    Bs[d] = Bmp[row0 * 16 + d];                 // 512 = 32*16 floats
    float Av[16];
#pragma unroll
    for (int n = 0; n < 16; n += 4) {
        float4 al = *(const float4*)&A_log[d * 16 + n];
        Av[n + 0] = -__expf(al.x);
        Av[n + 1] = -__expf(al.y);
        Av[n + 2] = -__expf(al.z);
        Av[n + 3] = -__expf(al.w);
    }
    __syncthreads();

    const float* dtp = dt + row0 * 512 + d;
    const __hip_bfloat16* up = u + row0 * 512 + d;
    float h[16] = {};
    float dtsum = 0.f;
    for (int t = 0; t < CHUNK; ++t) {
        float dtv = dtp[(size_t)t * 512];
        float uv = __bfloat162float(up[(size_t)t * 512]);
        float dtu = dtv * uv;
        dtsum += dtv;
        const float* Bt = &Bs[t * 16];
#pragma unroll
        for (int n = 0; n < 16; ++n)
            h[n] = fmaf(h[n], __expf(dtv * Av[n]), dtu * Bt[n]);
    }
    const size_t idx = (((size_t)b * NCHUNK + chunk) * 512 + d) * 16;
#pragma unroll
    for (int n = 0; n < 16; n += 4)
        *(float4*)&hpart[idx + n] = make_float4(h[n], h[n + 1], h[n + 2], h[n + 3]);
#pragma unroll
    for (int n = 0; n < 16; n += 4)
        *(float4*)&decay[idx + n] = make_float4(
            __expf(Av[n] * dtsum), __expf(Av[n + 1] * dtsum),
            __expf(Av[n + 2] * dtsum), __expf(Av[n + 3] * dtsum));
}

__global__ __launch_bounds__(256) void k_scan_comb(
    const float* __restrict__ hpart, const float* __restrict__ decay,
    float* __restrict__ h_in)
{
    const int gid = blockIdx.x * 256 + threadIdx.x;  // (b,d,n) = 16384 chains
    const int n = gid & 15;
    const int d = (gid >> 4) & 511;
    const int b = gid >> 13;
    float h = 0.f;
    for (int c = 0; c < NCHUNK; ++c) {
        const size_t idx = (((size_t)b * NCHUNK + c) * 512 + d) * 16 + n;
        h_in[idx] = h;
        h = fmaf(h, decay[idx], hpart[idx]);
    }
}

__global__ __launch_bounds__(512) void k_scan_fin(
    const float* __restrict__ dt, const __hip_bfloat16* __restrict__ u,
    const float* __restrict__ Bmp, const float* __restrict__ Cmp,
    const float* __restrict__ A_log, const float* __restrict__ Dp,
    const __hip_bfloat16* __restrict__ zs, const float* __restrict__ h_in,
    __hip_bfloat16* __restrict__ yout)
{
    __shared__ float Bs[CHUNK * 16];
    __shared__ float Cs[CHUNK * 16];
    const int d = threadIdx.x;
    const int chunk = blockIdx.x & (NCHUNK - 1);
    const int b = blockIdx.x >> 7;
    const size_t row0 = (size_t)b * 4096 + (size_t)chunk * CHUNK;

    Bs[d] = Bmp[row0 * 16 + d];
    Cs[d] = Cmp[row0 * 16 + d];
    float Av[16];
#pragma unroll
    for (int n = 0; n < 16; n += 4) {
        float4 al = *(const float4*)&A_log[d * 16 + n];
        Av[n + 0] = -__expf(al.x);
        Av[n + 1] = -__expf(al.y);
        Av[n + 2] = -__expf(al.z);
        Av[n + 3] = -__expf(al.w);
    }
    const float Dv = Dp[d];
    float h[16];
    const size_t idx = (((size_t)b * NCHUNK + chunk) * 512 + d) * 16;
#pragma unroll
    for (int n = 0; n < 16; n += 4) {
        float4 hv = *(const float4*)&h_in[idx + n];
        h[n] = hv.x; h[n + 1] = hv.y; h[n + 2] = hv.z; h[n + 3] = hv.w;
    }
    __syncthreads();

    const float* dtp = dt + row0 * 512 + d;
    const __hip_bfloat16* up = u + row0 * 512 + d;
    const __hip_bfloat16* zp = zs + row0 * 512 + d;
    __hip_bfloat16* yp = yout + row0 * 512 + d;
    for (int t = 0; t < CHUNK; ++t) {
        float dtv = dtp[(size_t)t * 512];
        float uv = __bfloat162float(up[(size_t)t * 512]);
        float zv = __bfloat162float(zp[(size_t)t * 512]);
        float dtu = dtv * uv;
        const float* Bt = &Bs[t * 16];
        const float* Ct = &Cs[t * 16];
        float y = 0.f;
#pragma unroll
        for (int n = 0; n < 16; ++n) {
            h[n] = fmaf(h[n], __expf(dtv * Av[n]), dtu * Bt[n]);
            y = fmaf(h[n], Ct[n], y);
        }
        yp[(size_t)t * 512] = __float2bfloat16((y + uv * Dv) * zv);
    }
}

// ---------------------------------------------------------------------------
// LayerNorm over C=256 + transposed write to (B,C,H,W).
// ---------------------------------------------------------------------------
__global__ __launch_bounds__(256) void k_ln_t(
    const float* __restrict__ res, const float* __restrict__ ln_g,
    const float* __restrict__ ln_b, float* __restrict__ outp)
{
    __shared__ float r[64 * 257];
    __shared__ float red[64][8];
    __shared__ float mu_s[64], sc_s[64];
    const int tid = threadIdx.x;
    const int b = blockIdx.x >> 6;
    const int l0 = (blockIdx.x & 63) * 64;
    const size_t base = ((size_t)b * 4096 + l0) * 256;

    for (int e = tid; e < 64 * 256; e += 256) {
        int i = e >> 8;
        int c = e & 255;
        r[i * 257 + c] = res[base + (size_t)i * 256 + c];
    }
    __syncthreads();
    {
        int i = tid >> 2, s = tid & 3;
        float ps = 0.f, pq = 0.f;
        for (int c = s * 64; c < s * 64 + 64; ++c) {
            float v = r[i * 257 + c];
            ps += v;
            pq = fmaf(v, v, pq);
        }
        red[i][s] = ps;
        red[i][4 + s] = pq;
    }
    __syncthreads();
    if (tid < 64) {
        float ps = red[tid][0] + red[tid][1] + red[tid][2] + red[tid][3];
        float pq = red[tid][4] + red[tid][5] + red[tid][6] + red[tid][7];
        float mu = ps * (1.0f / 256.0f);
        float var = pq * (1.0f / 256.0f) - mu * mu;
        mu_s[tid] = mu;
        sc_s[tid] = rsqrtf(var + 1e-5f);
    }
    __syncthreads();
    const int il = tid & 63;
    const int cg = tid >> 6;
    const float mu = mu_s[il], sc = sc_s[il];
    for (int c = cg; c < 256; c += 4) {
        float v = (r[il * 257 + c] - mu) * sc * ln_g[c] + ln_b[c];
        outp[(size_t)b * (256 * 4096) + (size_t)c * 4096 + l0 + il] = v;
    }
}

// ---------------------------------------------------------------------------
extern "C" void kernel_launch(void* const* d_in, const int* in_sizes, int n_in,
                              void* d_out, int out_size, void* d_ws, size_t ws_size,
                              hipStream_t stream)
{
    const float* decoder_feat = (const float*)d_in[0];
    const float* encoder_feat = (const float*)d_in[1];
    const float* dec_w = (const float*)d_in[2];
    const float* dec_b = (const float*)d_in[3];
    const float* enc_w = (const float*)d_in[4];
    const float* enc_b = (const float*)d_in[5];
    const float* out_w = (const float*)d_in[6];
    const float* out_b = (const float*)d_in[7];
    const float* ln_g = (const float*)d_in[8];
    const float* ln_bb = (const float*)d_in[9];
    const float* in_w = (const float*)d_in[10];
    const float* in_b = (const float*)d_in[11];
    const float* conv_w = (const float*)d_in[12];
    const float* conv_b = (const float*)d_in[13];
    const float* x_proj_w = (const float*)d_in[14];
    const float* dt_w = (const float*)d_in[15];
    const float* dt_b = (const float*)d_in[16];
    const float* A_log = (const float*)d_in[17];
    const float* D_param = (const float*)d_in[18];
    const float* m_out_w = (const float*)d_in[19];
    const float* m_out_b = (const float*)d_in[20];

    float* outp = (float*)d_out;
    char* ws = (char*)d_ws;
    const size_t MB = 1024ull * 1024;
    __hip_bfloat16* decL     = (__hip_bfloat16*)(ws + 0 * MB);    // 4 MB
    __hip_bfloat16* encL     = (__hip_bfloat16*)(ws + 4 * MB);    // 4 MB
    __hip_bfloat16* dec_wT   = (__hip_bfloat16*)(ws + 8 * MB);
    __hip_bfloat16* enc_wT   = (__hip_bfloat16*)(ws + 9 * MB);
    __hip_bfloat16* in_wT    = (__hip_bfloat16*)(ws + 10 * MB);
    __hip_bfloat16* m_out_wT = (__hip_bfloat16*)(ws + 11 * MB);
    __hip_bfloat16* out_wT   = (__hip_bfloat16*)(ws + 12 * MB);
    float* enc_p   = (float*)(ws + 13 * MB);                      // 16 MB; reused: hpart+decay
    __hip_bfloat16* combined = (__hip_bfloat16*)(ws + 29 * MB);   // 8 MB; reused: y
    float* dec_gate = (float*)(ws + 37 * MB);                     // 16 MB
    __hip_bfloat16* xm = (__hip_bfloat16*)(ws + 53 * MB);         // 8 MB; reused: h_in, then gated
    __hip_bfloat16* z_silu = (__hip_bfloat16*)(ws + 61 * MB);     // 8 MB
    __hip_bfloat16* u_buf = (__hip_bfloat16*)(ws + 69 * MB);      // 8 MB
    float* dt_buf = (float*)(ws + 77 * MB);                       // 16 MB; reused: res
    float* Bm = (float*)(ws + 93 * MB);                           // 0.5 MB
    float* Cm = (float*)(ws + 93 * MB + 524288);                  // 0.5 MB
    // scan scratch: 3 x 8 MB (2*128*512*16 floats each)
    float* hpart = enc_p;                 // enc_p dead after bgemm<1>
    float* decay = enc_p + 2097152;       // second half of enc_p slot
    float* h_in  = (float*)xm;            // xm dead after k_conv_proj
    __hip_bfloat16* y_buf = combined;
    __hip_bfloat16* gated = xm;           // written after fin reads h_in
    float* res = dt_buf;

    k_cast_w<<<5120, 256, 0, stream>>>(dec_w, enc_w, in_w, m_out_w, out_w,
                                       dec_wT, enc_wT, in_wT, m_out_wT, out_wT);
    k_tr_in<<<1024, 256, 0, stream>>>(decoder_feat, encoder_feat, decL, encL);
    bgemm<0, 256><<<dim3(4, 64), 256, 0, stream>>>(
        encL, enc_wT, enc_b, enc_p, nullptr, nullptr);
    bgemm<1, 256><<<dim3(8, 64), 256, 0, stream>>>(
        decL, dec_wT, dec_b, combined, dec_gate, enc_p);
    bgemm<2, 512><<<dim3(8, 64), 256, 0, stream>>>(
        combined, in_wT, in_b, xm, z_silu, nullptr);
    k_conv_proj<<<2048, 256, 0, stream>>>(
        xm, conv_w, conv_b, x_proj_w, dt_w, dt_b, u_buf, Bm, Cm, dt_buf);
    k_scan_part<<<2 * NCHUNK, 512, 0, stream>>>(dt_buf, u_buf, Bm, A_log, hpart, decay);
    k_scan_comb<<<64, 256, 0, stream>>>(hpart, decay, h_in);
    k_scan_fin<<<2 * NCHUNK, 512, 0, stream>>>(
        dt_buf, u_buf, Bm, Cm, A_log, D_param, z_silu, h_in, y_buf);
    bgemm<3, 512><<<dim3(4, 64), 256, 0, stream>>>(
        y_buf, m_out_wT, m_out_b, gated, nullptr, dec_gate);
    bgemm<4, 512><<<dim3(2, 64), 256, 0, stream>>>(
        gated, out_wT, out_b, res, nullptr, decL);
    k_ln_t<<<128, 256, 0, stream>>>(res, ln_g, ln_bb, outp);
}

// Round 5
// 297.113 us; speedup vs baseline: 7.6608x; 1.0527x over previous
//
#include <hip/hip_runtime.h>
#include <hip/hip_bf16.h>

typedef __bf16 bf16x8_t __attribute__((ext_vector_type(8)));
typedef float f32x4_t __attribute__((ext_vector_type(4)));

__device__ __forceinline__ float sigmoidf_(float x) { return 1.0f / (1.0f + __expf(-x)); }
__device__ __forceinline__ float siluf_(float x) { return x * sigmoidf_(x); }
__device__ __forceinline__ float softplusf_(float x) {
    return fmaxf(x, 0.0f) + log1pf(__expf(-fabsf(x)));
}
__device__ __forceinline__ float b2f(ushort u) { return __uint_as_float(((unsigned)u) << 16); }

// ---------------------------------------------------------------------------
// Cast + transpose weights fp32 [K][N] -> bf16 [N][K].
// dec_w(256x1024) enc_w(256x512) in_w(512x1024) m_out_w(512x512) out_w(512x256)
// x_proj_w(512x64) dt_w(32x512). Total 1,359,872 elems = 5312 blocks x 256.
// ---------------------------------------------------------------------------
__global__ __launch_bounds__(256) void k_cast_w(
    const float* __restrict__ dec_w, const float* __restrict__ enc_w,
    const float* __restrict__ in_w, const float* __restrict__ m_out_w,
    const float* __restrict__ out_w, const float* __restrict__ x_proj_w,
    const float* __restrict__ dt_w,
    __hip_bfloat16* __restrict__ dec_wT, __hip_bfloat16* __restrict__ enc_wT,
    __hip_bfloat16* __restrict__ in_wT, __hip_bfloat16* __restrict__ m_out_wT,
    __hip_bfloat16* __restrict__ out_wT, __hip_bfloat16* __restrict__ xpwT,
    __hip_bfloat16* __restrict__ dtwT)
{
    int gid = blockIdx.x * 256 + threadIdx.x;
    const float* src; __hip_bfloat16* dst; int lk, N, idx;
    if (gid < 262144)       { src = dec_w;    dst = dec_wT;   lk = 8; N = 1024; idx = gid; }
    else if (gid < 393216)  { src = enc_w;    dst = enc_wT;   lk = 8; N = 512;  idx = gid - 262144; }
    else if (gid < 917504)  { src = in_w;     dst = in_wT;    lk = 9; N = 1024; idx = gid - 393216; }
    else if (gid < 1179648) { src = m_out_w;  dst = m_out_wT; lk = 9; N = 512;  idx = gid - 917504; }
    else if (gid < 1310720) { src = out_w;    dst = out_wT;   lk = 9; N = 256;  idx = gid - 1179648; }
    else if (gid < 1343488) { src = x_proj_w; dst = xpwT;     lk = 9; N = 64;   idx = gid - 1310720; }
    else                    { src = dt_w;     dst = dtwT;     lk = 5; N = 512;  idx = gid - 1343488; }
    int K = 1 << lk;
    int n = idx >> lk, k = idx & (K - 1);
    dst[idx] = __float2bfloat16(src[(size_t)k * N + n]);
}

// ---------------------------------------------------------------------------
// Transpose inputs (b,c,l) fp32 -> (b,l,c) bf16 for dec and enc.
// ---------------------------------------------------------------------------
__global__ __launch_bounds__(256) void k_tr_in(
    const float* __restrict__ dec, const float* __restrict__ enc,
    __hip_bfloat16* __restrict__ decL, __hip_bfloat16* __restrict__ encL)
{
    __shared__ float tile[64][65];
    const int t = threadIdx.x;
    const int ct = blockIdx.x & 3;
    const int lt = (blockIdx.x >> 2) & 63;
    const int sel = blockIdx.x >> 8;
    const int b = sel & 1, ten = sel >> 1;
    const float* src = ten ? enc : dec;
    __hip_bfloat16* dst = ten ? encL : decL;
    const size_t ibase = (size_t)b * 256 * 4096 + (size_t)(ct * 64) * 4096 + (size_t)lt * 64;
#pragma unroll
    for (int i = 0; i < 16; ++i) {
        int c = i * 4 + (t >> 6), l = t & 63;
        tile[c][l] = src[ibase + (size_t)c * 4096 + l];
    }
    __syncthreads();
    const size_t obase = ((size_t)b * 4096 + (size_t)lt * 64) * 256 + ct * 64;
#pragma unroll
    for (int i = 0; i < 16; ++i) {
        int l = i * 4 + (t >> 6), c = t & 63;
        dst[obase + (size_t)l * 256 + c] = __float2bfloat16(tile[c][l]);
    }
}

// ---------------------------------------------------------------------------
// bf16 MFMA GEMM (128x128 tile, BK=32, 4 waves of 64x64).
// EPI 0: enc_p bf16 | EPI 1: combined bf16 + sigmoid(gate) bf16 (extra=enc_p bf16)
// EPI 2: xm/silu(z) bf16 | EPI 3: * gate bf16 | EPI 4: + residual f32
// ---------------------------------------------------------------------------
template <int EPI, int K>
__global__ __launch_bounds__(256) void bgemm(
    const __hip_bfloat16* __restrict__ A, const __hip_bfloat16* __restrict__ Bt,
    const float* __restrict__ bias, void* __restrict__ out0,
    void* __restrict__ out1, const void* __restrict__ extra)
{
    __shared__ ushort At[128 * 32];
    __shared__ ushort Bl[128 * 32];
    const int tid = threadIdx.x;
    const int wave = tid >> 6, lane = tid & 63;
    const int n0 = blockIdx.x * 128, m0 = blockIdx.y * 128;
    const int wm = (wave >> 1) * 64, wn = (wave & 1) * 64;
    f32x4_t acc[4][4] = {};
    const int fr = lane & 15, fq = (lane >> 4) * 8;

    for (int k0 = 0; k0 < K; k0 += 32) {
#pragma unroll
        for (int q = 0; q < 2; ++q) {
            int idx = q * 256 + tid;
            int row = idx >> 2, ch = (idx & 3) * 8;
            uint4 va = *(const uint4*)&A[(size_t)(m0 + row) * K + k0 + ch];
            uint4 vb = *(const uint4*)&Bt[(size_t)(n0 + row) * K + k0 + ch];
            *(uint4*)&At[row * 32 + ch] = va;
            *(uint4*)&Bl[row * 32 + ch] = vb;
        }
        __syncthreads();
        bf16x8_t af[4], bf[4];
#pragma unroll
        for (int i = 0; i < 4; ++i) {
            af[i] = *(bf16x8_t*)&At[(wm + i * 16 + fr) * 32 + fq];
            bf[i] = *(bf16x8_t*)&Bl[(wn + i * 16 + fr) * 32 + fq];
        }
#pragma unroll
        for (int i = 0; i < 4; ++i)
#pragma unroll
            for (int j = 0; j < 4; ++j)
                acc[i][j] = __builtin_amdgcn_mfma_f32_16x16x32_bf16(af[i], bf[j], acc[i][j], 0, 0, 0);
        __syncthreads();
    }

    const int col = lane & 15, rbase = (lane >> 4) * 4;
#pragma unroll
    for (int i = 0; i < 4; ++i) {
#pragma unroll
        for (int j = 0; j < 4; ++j) {
#pragma unroll
            for (int r = 0; r < 4; ++r) {
                int m = m0 + wm + i * 16 + rbase + r;
                int n = n0 + wn + j * 16 + col;
                float v = acc[i][j][r] + bias[n];
                if (EPI == 0) {
                    ((__hip_bfloat16*)out0)[(size_t)m * 512 + n] = __float2bfloat16(v);
                } else if (EPI == 1) {
                    if (n < 512) {
                        float ep = __bfloat162float(((const __hip_bfloat16*)extra)[(size_t)m * 512 + n]);
                        ((__hip_bfloat16*)out0)[(size_t)m * 512 + n] =
                            __float2bfloat16(fmaf(v, sigmoidf_(ep), ep));
                    } else {
                        ((__hip_bfloat16*)out1)[(size_t)m * 512 + (n - 512)] =
                            __float2bfloat16(sigmoidf_(v));
                    }
                } else if (EPI == 2) {
                    if (n < 512)
                        ((__hip_bfloat16*)out0)[(size_t)m * 512 + n] = __float2bfloat16(v);
                    else
                        ((__hip_bfloat16*)out1)[(size_t)m * 512 + (n - 512)] =
                            __float2bfloat16(siluf_(v));
                } else if (EPI == 3) {
                    float g = __bfloat162float(((const __hip_bfloat16*)extra)[(size_t)m * 512 + n]);
                    ((__hip_bfloat16*)out0)[(size_t)m * 512 + n] = __float2bfloat16(v * g);
                } else {
                    float dv = __bfloat162float(((const __hip_bfloat16*)extra)[(size_t)m * 256 + n]);
                    ((float*)out0)[(size_t)m * 256 + n] = v + dv;
                }
            }
        }
    }
}

// ---------------------------------------------------------------------------
// Conv + projections, MFMA version. Block = 16 rows, 256 threads (4 waves).
// Phase 1: depthwise causal conv(K=4)+silu -> u (LDS bf16 tile + global).
// Phase 2: x_dbl = u(16x512) @ x_proj_wT(64x512)^T via MFMA (4 waves x 1 tile).
//          n<32 -> LDS (dt input), 32..47 -> Bm, 48..63 -> Cm.
// Phase 3: dt_raw = x_dbl[:, :32] @ dt_wT(512x32)^T via MFMA (K=32, 1 inst),
//          dt = softplus(dt_raw + dt_b) -> global fp32.
// ---------------------------------------------------------------------------
#define CROWS 16
__global__ __launch_bounds__(256) void k_conv_proj(
    const __hip_bfloat16* __restrict__ xm, const float* __restrict__ conv_w,
    const float* __restrict__ conv_b, const __hip_bfloat16* __restrict__ xpwT,
    const __hip_bfloat16* __restrict__ dtwT, const float* __restrict__ dt_b,
    __hip_bfloat16* __restrict__ u_out, float* __restrict__ Bm,
    float* __restrict__ Cm, float* __restrict__ dt_out)
{
    __shared__ ushort ut[CROWS][512 + 8];   // u bf16, +8 pad: ds_read_b128 2-way only
    __shared__ ushort adt[CROWS][32 + 8];   // x_dbl[:, :32] bf16
    const int tid = threadIdx.x;
    const int wave = tid >> 6, lane = tid & 63;
    const int bl0 = blockIdx.x * CROWS;
    const int l0 = bl0 & 4095;
    const int fr = lane & 15, fq = (lane >> 4) * 8;
    const int col = lane & 15, rbase = (lane >> 4) * 4;

    // ---- phase 1: conv (thread handles d0 = 2*tid, d0+1)
    {
        const int d0 = tid * 2;
        float cw0[4], cw1[4];
#pragma unroll
        for (int k = 0; k < 4; ++k) {
            cw0[k] = conv_w[d0 * 4 + k];
            cw1[k] = conv_w[d0 * 4 + 4 + k];
        }
        const float cb0 = conv_b[d0], cb1 = conv_b[d0 + 1];
        float xa[CROWS + 3], xb[CROWS + 3];
        const ushort* xs = (const ushort*)xm;
#pragma unroll
        for (int i = 0; i < CROWS + 3; ++i) {
            if (l0 - 3 + i >= 0) {
                ushort2 v = *(const ushort2*)&xs[(size_t)(bl0 - 3 + i) * 512 + d0];
                xa[i] = b2f(v.x); xb[i] = b2f(v.y);
            } else { xa[i] = 0.f; xb[i] = 0.f; }
        }
#pragma unroll
        for (int r = 0; r < CROWS; ++r) {
            float a = cb0, b = cb1;
#pragma unroll
            for (int k = 0; k < 4; ++k) {
                a = fmaf(cw0[k], xa[r + k], a);
                b = fmaf(cw1[k], xb[r + k], b);
            }
            float ua = siluf_(a), ub = siluf_(b);
            ushort2 up = make_ushort2(
                (ushort)(__bfloat16_as_ushort(__float2bfloat16(ua))),
                (ushort)(__bfloat16_as_ushort(__float2bfloat16(ub))));
            *(ushort2*)&ut[r][d0] = up;
            *(ushort2*)&((ushort*)u_out)[(size_t)(bl0 + r) * 512 + d0] = up;
        }
    }
    __syncthreads();

    // ---- phase 2: x_dbl MFMA. wave w handles n-tile [w*16, w*16+16)
    {
        f32x4_t acc = {};
        const __hip_bfloat16* bp = xpwT + (size_t)(wave * 16 + fr) * 512;
#pragma unroll
        for (int k0 = 0; k0 < 512; k0 += 32) {
            bf16x8_t af = *(bf16x8_t*)&ut[fr][k0 + fq];
            bf16x8_t bf = *(const bf16x8_t*)&bp[k0 + fq];
            acc = __builtin_amdgcn_mfma_f32_16x16x32_bf16(af, bf, acc, 0, 0, 0);
        }
#pragma unroll
        for (int r = 0; r < 4; ++r) {
            int m = rbase + r;
            int n = wave * 16 + col;
            float v = acc[r];
            if (n < 32)      adt[m][n] = (ushort)__bfloat16_as_ushort(__float2bfloat16(v));
            else if (n < 48) Bm[(size_t)(bl0 + m) * 16 + (n - 32)] = v;
            else             Cm[(size_t)(bl0 + m) * 16 + (n - 48)] = v;
        }
    }
    __syncthreads();

    // ---- phase 3: dt MFMA (M=16, N=512, K=32). wave w: n-tiles w*8..w*8+7
    {
        bf16x8_t af = *(bf16x8_t*)&adt[fr][fq];
#pragma unroll
        for (int t = 0; t < 8; ++t) {
            int nt = wave * 8 + t;
            bf16x8_t bf = *(const bf16x8_t*)&dtwT[(size_t)(nt * 16 + fr) * 32 + fq];
            f32x4_t acc = {};
            acc = __builtin_amdgcn_mfma_f32_16x16x32_bf16(af, bf, acc, 0, 0, 0);
#pragma unroll
            for (int r = 0; r < 4; ++r) {
                int m = rbase + r;
                int n = nt * 16 + col;
                dt_out[(size_t)(bl0 + m) * 512 + n] = softplusf_(acc[r] + dt_b[n]);
            }
        }
    }
}

// ---------------------------------------------------------------------------
// Chunked parallel scan, thread-per-(b,chunk,d), N=16 state in registers.
// ---------------------------------------------------------------------------
#define CHUNK 32
#define NCHUNK 128

__global__ __launch_bounds__(512) void k_scan_part(
    const float* __restrict__ dt, const __hip_bfloat16* __restrict__ u,
    const float* __restrict__ Bmp, const float* __restrict__ A_log,
    float* __restrict__ hpart, float* __restrict__ decay)
{
    __shared__ float Bs[CHUNK * 16];
    const int d = threadIdx.x;
    const int chunk = blockIdx.x & (NCHUNK - 1);
    const int b = blockIdx.x >> 7;
    const size_t row0 = (size_t)b * 4096 + (size_t)chunk * CHUNK;

    Bs[d] = Bmp[row0 * 16 + d];
    float Av[16];
#pragma unroll
    for (int n = 0; n < 16; n += 4) {
        float4 al = *(const float4*)&A_log[d * 16 + n];
        Av[n + 0] = -__expf(al.x);
        Av[n + 1] = -__expf(al.y);
        Av[n + 2] = -__expf(al.z);
        Av[n + 3] = -__expf(al.w);
    }
    __syncthreads();

    const float* dtp = dt + row0 * 512 + d;
    const __hip_bfloat16* up = u + row0 * 512 + d;
    float h[16] = {};
    float dtsum = 0.f;
    for (int t = 0; t < CHUNK; ++t) {
        float dtv = dtp[(size_t)t * 512];
        float uv = __bfloat162float(up[(size_t)t * 512]);
        float dtu = dtv * uv;
        dtsum += dtv;
        const float* Bt = &Bs[t * 16];
#pragma unroll
        for (int n = 0; n < 16; ++n)
            h[n] = fmaf(h[n], __expf(dtv * Av[n]), dtu * Bt[n]);
    }
    const size_t idx = (((size_t)b * NCHUNK + chunk) * 512 + d) * 16;
#pragma unroll
    for (int n = 0; n < 16; n += 4)
        *(float4*)&hpart[idx + n] = make_float4(h[n], h[n + 1], h[n + 2], h[n + 3]);
#pragma unroll
    for (int n = 0; n < 16; n += 4)
        *(float4*)&decay[idx + n] = make_float4(
            __expf(Av[n] * dtsum), __expf(Av[n + 1] * dtsum),
            __expf(Av[n + 2] * dtsum), __expf(Av[n + 3] * dtsum));
}

__global__ __launch_bounds__(256) void k_scan_comb(
    const float* __restrict__ hpart, const float* __restrict__ decay,
    float* __restrict__ h_in)
{
    const int gid = blockIdx.x * 256 + threadIdx.x;
    const int n = gid & 15;
    const int d = (gid >> 4) & 511;
    const int b = gid >> 13;
    float h = 0.f;
    for (int c = 0; c < NCHUNK; ++c) {
        const size_t idx = (((size_t)b * NCHUNK + c) * 512 + d) * 16 + n;
        h_in[idx] = h;
        h = fmaf(h, decay[idx], hpart[idx]);
    }
}

__global__ __launch_bounds__(512) void k_scan_fin(
    const float* __restrict__ dt, const __hip_bfloat16* __restrict__ u,
    const float* __restrict__ Bmp, const float* __restrict__ Cmp,
    const float* __restrict__ A_log, const float* __restrict__ Dp,
    const __hip_bfloat16* __restrict__ zs, const float* __restrict__ h_in,
    __hip_bfloat16* __restrict__ yout)
{
    __shared__ float Bs[CHUNK * 16];
    __shared__ float Cs[CHUNK * 16];
    const int d = threadIdx.x;
    const int chunk = blockIdx.x & (NCHUNK - 1);
    const int b = blockIdx.x >> 7;
    const size_t row0 = (size_t)b * 4096 + (size_t)chunk * CHUNK;

    Bs[d] = Bmp[row0 * 16 + d];
    Cs[d] = Cmp[row0 * 16 + d];
    float Av[16];
#pragma unroll
    for (int n = 0; n < 16; n += 4) {
        float4 al = *(const float4*)&A_log[d * 16 + n];
        Av[n + 0] = -__expf(al.x);
        Av[n + 1] = -__expf(al.y);
        Av[n + 2] = -__expf(al.z);
        Av[n + 3] = -__expf(al.w);
    }
    const float Dv = Dp[d];
    float h[16];
    const size_t idx = (((size_t)b * NCHUNK + chunk) * 512 + d) * 16;
#pragma unroll
    for (int n = 0; n < 16; n += 4) {
        float4 hv = *(const float4*)&h_in[idx + n];
        h[n] = hv.x; h[n + 1] = hv.y; h[n + 2] = hv.z; h[n + 3] = hv.w;
    }
    __syncthreads();

    const float* dtp = dt + row0 * 512 + d;
    const __hip_bfloat16* up = u + row0 * 512 + d;
    const __hip_bfloat16* zp = zs + row0 * 512 + d;
    __hip_bfloat16* yp = yout + row0 * 512 + d;
    for (int t = 0; t < CHUNK; ++t) {
        float dtv = dtp[(size_t)t * 512];
        float uv = __bfloat162float(up[(size_t)t * 512]);
        float zv = __bfloat162float(zp[(size_t)t * 512]);
        float dtu = dtv * uv;
        const float* Bt = &Bs[t * 16];
        const float* Ct = &Cs[t * 16];
        float y = 0.f;
#pragma unroll
        for (int n = 0; n < 16; ++n) {
            h[n] = fmaf(h[n], __expf(dtv * Av[n]), dtu * Bt[n]);
            y = fmaf(h[n], Ct[n], y);
        }
        yp[(size_t)t * 512] = __float2bfloat16((y + uv * Dv) * zv);
    }
}

// ---------------------------------------------------------------------------
// LayerNorm over C=256 + transposed write to (B,C,H,W).
// ---------------------------------------------------------------------------
__global__ __launch_bounds__(256) void k_ln_t(
    const float* __restrict__ res, const float* __restrict__ ln_g,
    const float* __restrict__ ln_b, float* __restrict__ outp)
{
    __shared__ float r[64 * 257];
    __shared__ float red[64][8];
    __shared__ float mu_s[64], sc_s[64];
    const int tid = threadIdx.x;
    const int b = blockIdx.x >> 6;
    const int l0 = (blockIdx.x & 63) * 64;
    const size_t base = ((size_t)b * 4096 + l0) * 256;

    for (int e = tid; e < 64 * 256; e += 256) {
        int i = e >> 8;
        int c = e & 255;
        r[i * 257 + c] = res[base + (size_t)i * 256 + c];
    }
    __syncthreads();
    {
        int i = tid >> 2, s = tid & 3;
        float ps = 0.f, pq = 0.f;
        for (int c = s * 64; c < s * 64 + 64; ++c) {
            float v = r[i * 257 + c];
            ps += v;
            pq = fmaf(v, v, pq);
        }
        red[i][s] = ps;
        red[i][4 + s] = pq;
    }
    __syncthreads();
    if (tid < 64) {
        float ps = red[tid][0] + red[tid][1] + red[tid][2] + red[tid][3];
        float pq = red[tid][4] + red[tid][5] + red[tid][6] + red[tid][7];
        float mu = ps * (1.0f / 256.0f);
        float var = pq * (1.0f / 256.0f) - mu * mu;
        mu_s[tid] = mu;
        sc_s[tid] = rsqrtf(var + 1e-5f);
    }
    __syncthreads();
    const int il = tid & 63;
    const int cg = tid >> 6;
    const float mu = mu_s[il], sc = sc_s[il];
    for (int c = cg; c < 256; c += 4) {
        float v = (r[il * 257 + c] - mu) * sc * ln_g[c] + ln_b[c];
        outp[(size_t)b * (256 * 4096) + (size_t)c * 4096 + l0 + il] = v;
    }
}

// ---------------------------------------------------------------------------
extern "C" void kernel_launch(void* const* d_in, const int* in_sizes, int n_in,
                              void* d_out, int out_size, void* d_ws, size_t ws_size,
                              hipStream_t stream)
{
    const float* decoder_feat = (const float*)d_in[0];
    const float* encoder_feat = (const float*)d_in[1];
    const float* dec_w = (const float*)d_in[2];
    const float* dec_b = (const float*)d_in[3];
    const float* enc_w = (const float*)d_in[4];
    const float* enc_b = (const float*)d_in[5];
    const float* out_w = (const float*)d_in[6];
    const float* out_b = (const float*)d_in[7];
    const float* ln_g = (const float*)d_in[8];
    const float* ln_bb = (const float*)d_in[9];
    const float* in_w = (const float*)d_in[10];
    const float* in_b = (const float*)d_in[11];
    const float* conv_w = (const float*)d_in[12];
    const float* conv_b = (const float*)d_in[13];
    const float* x_proj_w = (const float*)d_in[14];
    const float* dt_w = (const float*)d_in[15];
    const float* dt_b = (const float*)d_in[16];
    const float* A_log = (const float*)d_in[17];
    const float* D_param = (const float*)d_in[18];
    const float* m_out_w = (const float*)d_in[19];
    const float* m_out_b = (const float*)d_in[20];

    float* outp = (float*)d_out;
    char* ws = (char*)d_ws;
    const size_t MB = 1024ull * 1024;
    __hip_bfloat16* decL     = (__hip_bfloat16*)(ws + 0 * MB);    // 4 MB
    __hip_bfloat16* encL     = (__hip_bfloat16*)(ws + 4 * MB);    // 4 MB
    __hip_bfloat16* dec_wT   = (__hip_bfloat16*)(ws + 8 * MB);
    __hip_bfloat16* enc_wT   = (__hip_bfloat16*)(ws + 9 * MB);
    __hip_bfloat16* in_wT    = (__hip_bfloat16*)(ws + 10 * MB);
    __hip_bfloat16* m_out_wT = (__hip_bfloat16*)(ws + 11 * MB);
    __hip_bfloat16* out_wT   = (__hip_bfloat16*)(ws + 12 * MB);
    __hip_bfloat16* xpwT     = (__hip_bfloat16*)(ws + 12 * MB + 262144);          // 64 KB
    __hip_bfloat16* dtwT     = (__hip_bfloat16*)(ws + 12 * MB + 262144 + 65536);  // 32 KB
    __hip_bfloat16* enc_pb   = (__hip_bfloat16*)(ws + 13 * MB);   // 8 MB of 16-MB slot
    __hip_bfloat16* combined = (__hip_bfloat16*)(ws + 29 * MB);   // 8 MB; reused: y
    __hip_bfloat16* gate_sig = (__hip_bfloat16*)(ws + 37 * MB);   // 4 MB (sigmoid(gate) bf16)
    __hip_bfloat16* xm = (__hip_bfloat16*)(ws + 53 * MB);         // 8 MB; reused: h_in, gated
    __hip_bfloat16* z_silu = (__hip_bfloat16*)(ws + 61 * MB);     // 8 MB
    __hip_bfloat16* u_buf = (__hip_bfloat16*)(ws + 69 * MB);      // 8 MB
    float* dt_buf = (float*)(ws + 77 * MB);                       // 16 MB; reused: res
    float* Bm = (float*)(ws + 93 * MB);                           // 0.5 MB
    float* Cm = (float*)(ws + 93 * MB + 524288);                  // 0.5 MB
    // scan scratch (dead-slot reuse)
    float* hpart = (float*)(ws + 13 * MB);       // enc_pb dead after bgemm<1>
    float* decay = hpart + 2097152;
    float* h_in  = (float*)xm;                   // xm dead after k_conv_proj
    __hip_bfloat16* y_buf = combined;
    __hip_bfloat16* gated = xm;
    float* res = dt_buf;

    k_cast_w<<<5312, 256, 0, stream>>>(dec_w, enc_w, in_w, m_out_w, out_w, x_proj_w, dt_w,
                                       dec_wT, enc_wT, in_wT, m_out_wT, out_wT, xpwT, dtwT);
    k_tr_in<<<1024, 256, 0, stream>>>(decoder_feat, encoder_feat, decL, encL);
    bgemm<0, 256><<<dim3(4, 64), 256, 0, stream>>>(
        encL, enc_wT, enc_b, enc_pb, nullptr, nullptr);
    bgemm<1, 256><<<dim3(8, 64), 256, 0, stream>>>(
        decL, dec_wT, dec_b, combined, gate_sig, enc_pb);
    bgemm<2, 512><<<dim3(8, 64), 256, 0, stream>>>(
        combined, in_wT, in_b, xm, z_silu, nullptr);
    k_conv_proj<<<512, 256, 0, stream>>>(
        xm, conv_w, conv_b, xpwT, dtwT, dt_b, u_buf, Bm, Cm, dt_buf);
    k_scan_part<<<2 * NCHUNK, 512, 0, stream>>>(dt_buf, u_buf, Bm, A_log, hpart, decay);
    k_scan_comb<<<64, 256, 0, stream>>>(hpart, decay, h_in);
    k_scan_fin<<<2 * NCHUNK, 512, 0, stream>>>(
        dt_buf, u_buf, Bm, Cm, A_log, D_param, z_silu, h_in, y_buf);
    bgemm<3, 512><<<dim3(4, 64), 256, 0, stream>>>(
        y_buf, m_out_wT, m_out_b, gated, nullptr, gate_sig);
    bgemm<4, 512><<<dim3(2, 64), 256, 0, stream>>>(
        gated, out_wT, out_b, res, nullptr, decL);
    k_ln_t<<<128, 256, 0, stream>>>(res, ln_g, ln_bb, outp);
}